// Round 16
// baseline (467.416 us; speedup 1.0000x reference)
//
#include <hip/hip_runtime.h>
#include <hip/hip_bf16.h>
#include <stdint.h>

#define T_TOK 2048
#define H_DIM 2048
#define S_SEQ 1024
#define NE_ROUTED 8
#define NE 9
#define IMOE 1408
#define ISHARED 5632
#define UNCOND_LBL 1000

typedef short bf16x8 __attribute__((ext_vector_type(8)));
typedef float f32x4 __attribute__((ext_vector_type(4)));

__device__ __forceinline__ unsigned short f2bf(float f) {
  union { float f; unsigned int u; } v; v.f = f;
  unsigned int u = v.u;
  return (unsigned short)((u + 0x7fffu + ((u >> 16) & 1u)) >> 16);
}

__device__ __forceinline__ void gl16(const void* g, void* l) {
  __builtin_amdgcn_global_load_lds(
      (const __attribute__((address_space(1))) unsigned int*)g,
      (__attribute__((address_space(3))) unsigned int*)l, 16, 0, 0);
}

// ============================================================================
// Striped-swizzled bf16 layout: tensor[e][ns][kt][u][8], ns=n/16, kt=k/32,
// logical unit ul = (n&15)*4 + ((k>>3)&3), physical u = ul ^ ((ul>>3)&7).
// ============================================================================

__device__ __forceinline__ void transpose_body(
    const float* __restrict__ src, unsigned short* __restrict__ dst,
    int K, int N, int e, int kt, int n0, int t, float* tile /*[32][72]*/) {
  int NS = N >> 4, KT = K >> 5;
  const float* sp0 = src + (size_t)e * K * N + (size_t)kt * 32 * N + n0;
  int kr = t >> 3, nc = (t & 7) << 3;
  const float* sp = sp0 + (size_t)kr * N + nc;
  float4 a = *(const float4*)sp;
  float4 b = *(const float4*)(sp + 4);
  *(float4*)&tile[kr * 72 + nc] = a;
  *(float4*)&tile[kr * 72 + nc + 4] = b;
  __syncthreads();
  int nsl = t >> 6, up = t & 63;
  int ul = up ^ ((up >> 3) & 7);
  int rn = ul >> 2, fq = ul & 3;
  int nl = (nsl << 4) + rn;
  unsigned int pk[4];
#pragma unroll
  for (int j = 0; j < 4; j++) {
    float f0 = tile[(fq * 8 + 2 * j) * 72 + nl];
    float f1 = tile[(fq * 8 + 2 * j + 1) * 72 + nl];
    pk[j] = (unsigned)f2bf(f0) | ((unsigned)f2bf(f1) << 16);
  }
  size_t ns = (size_t)e * NS + (n0 >> 4) + nsl;
  unsigned short* dp = dst + (ns * KT + kt) * 512 + up * 8;
  *(uint4*)dp = make_uint4(pk[0], pk[1], pk[2], pk[3]);
}

// ============================================================================
// PREPASS: cvt(x->bf16) + router + all six weight transposes, ONE dispatch.
// ============================================================================
__global__ __launch_bounds__(256) void prepass(
    const float* __restrict__ x, const int* __restrict__ labels,
    const float* __restrict__ cc,
    const float* __restrict__ Wg, const float* __restrict__ Wu,
    const float* __restrict__ Wd, const float* __restrict__ Wgs,
    const float* __restrict__ Wus, const float* __restrict__ Wds,
    unsigned short* __restrict__ xbf,
    int* __restrict__ counts, int* __restrict__ toklist, float* __restrict__ wts,
    unsigned short* __restrict__ WgT, unsigned short* __restrict__ WuT,
    unsigned short* __restrict__ WdT, unsigned short* __restrict__ WgsT,
    unsigned short* __restrict__ WusT, unsigned short* __restrict__ WdsT) {
  __shared__ float tile[32 * 72];
  int blk = blockIdx.x;
  int tid = threadIdx.x;

  if (blk < 4096) {                       // ---- cvt ----
    int i = (blk * 256 + tid) * 4;
    float4 v = *(const float4*)(x + i);
    uint2 pk;
    pk.x = (unsigned)f2bf(v.x) | ((unsigned)f2bf(v.y) << 16);
    pk.y = (unsigned)f2bf(v.z) | ((unsigned)f2bf(v.w) << 16);
    *(uint2*)(xbf + i) = pk;
    return;
  }
  if (blk < 4608) {                       // ---- router ----
    int t = ((blk - 4096) * 256 + tid) >> 6;
    int lane = tid & 63;
    const float* xp = x + (size_t)t * H_DIM;
    float xx = 0.f;
    float d[NE_ROUTED], cn[NE_ROUTED];
#pragma unroll
    for (int e = 0; e < NE_ROUTED; e++) { d[e] = 0.f; cn[e] = 0.f; }
    for (int h = lane; h < H_DIM; h += 64) {
      float xv = xp[h];
      xx += xv * xv;
#pragma unroll
      for (int e = 0; e < NE_ROUTED; e++) {
        float cv = cc[e * H_DIM + h];
        d[e] += xv * cv;
        cn[e] += cv * cv;
      }
    }
#pragma unroll
    for (int off = 32; off > 0; off >>= 1) {
      xx += __shfl_xor(xx, off);
#pragma unroll
      for (int e = 0; e < NE_ROUTED; e++) {
        d[e] += __shfl_xor(d[e], off);
        cn[e] += __shfl_xor(cn[e], off);
      }
    }
    if (lane == 0) {
      int lab = labels[t / S_SEQ];
      if (lab == UNCOND_LBL) {
        int r = atomicAdd(&counts[NE - 1], 1);
        toklist[(NE - 1) * T_TOK + r] = t;
        wts[(NE - 1) * T_TOK + r] = 1.0f;
      } else {
        float xn = sqrtf(xx + 1e-12f);
        float cosv[NE_ROUTED];
        float mx = -1e30f;
#pragma unroll
        for (int e = 0; e < NE_ROUTED; e++) {
          cosv[e] = d[e] / (xn * sqrtf(cn[e] + 1e-12f));
          mx = fmaxf(mx, cosv[e]);
        }
        float p[NE_ROUTED];
        float s = 0.f;
#pragma unroll
        for (int e = 0; e < NE_ROUTED; e++) { p[e] = __expf(cosv[e] - mx); s += p[e]; }
        int i1 = 0;
#pragma unroll
        for (int e = 1; e < NE_ROUTED; e++) if (p[e] > p[i1]) i1 = e;
        int i2 = (i1 == 0) ? 1 : 0;
#pragma unroll
        for (int e = 0; e < NE_ROUTED; e++) if (e != i2 && e != i1 && p[e] > p[i2]) i2 = e;
        int r1 = atomicAdd(&counts[i1], 1);
        toklist[i1 * T_TOK + r1] = t;
        wts[i1 * T_TOK + r1] = p[i1] / s;
        int r2 = atomicAdd(&counts[i2], 1);
        toklist[i2 * T_TOK + r2] = t;
        wts[i2 * T_TOK + r2] = p[i2] / s;
      }
    }
    return;
  }
  int lid = blk - 4608;
  if (lid < 12672) {                       // Wg
    int e = lid / 1408, r = lid % 1408;
    int kt = r / 22, n0 = (r % 22) << 6;
    transpose_body(Wg, WgT, H_DIM, IMOE, e, kt, n0, tid, tile);
  } else if (lid < 25344) {                // Wu
    int r0 = lid - 12672;
    int e = r0 / 1408, r = r0 % 1408;
    int kt = r / 22, n0 = (r % 22) << 6;
    transpose_body(Wu, WuT, H_DIM, IMOE, e, kt, n0, tid, tile);
  } else if (lid < 38016) {                // Wd
    int r0 = lid - 25344;
    int e = r0 / 1408, r = r0 % 1408;
    int kt = r / 32, n0 = (r % 32) << 6;
    transpose_body(Wd, WdT, IMOE, H_DIM, e, kt, n0, tid, tile);
  } else if (lid < 43648) {                // Wgs
    int r = lid - 38016;
    int kt = r / 88, n0 = (r % 88) << 6;
    transpose_body(Wgs, WgsT, H_DIM, ISHARED, 0, kt, n0, tid, tile);
  } else if (lid < 49280) {                // Wus
    int r = lid - 43648;
    int kt = r / 88, n0 = (r % 88) << 6;
    transpose_body(Wus, WusT, H_DIM, ISHARED, 0, kt, n0, tid, tile);
  } else {                                 // Wds
    int r = lid - 49280;
    int kt = r / 32, n0 = (r % 32) << 6;
    transpose_body(Wds, WdsT, ISHARED, H_DIM, 0, kt, n0, tid, tile);
  }
}

// ---- inline descriptor lookup ----
__device__ __forceinline__ bool up_desc(const int* counts, int d,
                                        bool* sh, int* e, int* nt, int* mt) {
  int mtm[NE];
  int nv = 352;
#pragma unroll
  for (int k = 0; k < NE; k++) {
    int c = counts[k];
    int m = (c + 255) >> 8; if (m > 8) m = 8;
    mtm[k] = m;
    nv += m * 11;
  }
  int q = nv >> 3, r = nv & 7;
  int x = d & 7, j = d >> 3;
  int cap = q + (x < r ? 1 : 0);
  if (j >= cap) return false;
  int idx = (x < r ? x * (q + 1) : r * (q + 1) + (x - r) * q) + j;
  if (idx < 352) {
    *sh = true; *e = 0; *nt = idx >> 3; *mt = idx & 7;
    return true;
  }
  idx -= 352;
#pragma unroll
  for (int k = 0; k < NE; k++) {
    int n = mtm[k] * 11;
    if (idx < n) {
      *sh = false; *e = k; *nt = idx / mtm[k]; *mt = idx % mtm[k];
      return true;
    }
    idx -= n;
  }
  return false;
}

__device__ __forceinline__ bool down_desc(const int* counts, int d,
                                          bool* sh, int* e, int* nt, int* mt, int* kc) {
  int x = d & 7, j = d >> 3;
  if (j < 32) {
    *sh = true; *e = 0; *nt = x; *mt = j >> 1; *kc = j & 1;
    return true;
  }
  int mtm[NE];
  int R = 0;
#pragma unroll
  for (int k = 0; k < NE; k++) {
    int c = counts[k];
    int m = (c + 127) >> 7; if (m > 16) m = 16;
    mtm[k] = m;
    R += m * 8;
  }
  int jr = j - 32;
  int q = R >> 3, r = R & 7;
  int cap = q + (x < r ? 1 : 0);
  if (jr >= cap) return false;
  int idx = (x < r ? x * (q + 1) : r * (q + 1) + (x - r) * q) + jr;
#pragma unroll
  for (int k = 0; k < NE; k++) {
    int n = mtm[k] * 8;
    if (idx < n) {
      *sh = false; *e = k; *nt = idx / mtm[k]; *mt = idx % mtm[k]; *kc = 0;
      return true;
    }
    idx -= n;
  }
  return false;
}

// ============================================================================
// Merged fused gate+up GEMM — round-15 body with FINE-PHASE K-step (T3 port):
// each K-step = 2 full phases {ds_read ∥ 1 gl16 -> barrier -> lgkmcnt(0)+
// sched_barrier -> setprio MFMA cluster -> barrier}; counted vmcnt(4/2/0)
// once per step at phase 2. Buffer ring/lifetimes identical to round 15
// (strictly MORE synchronization -> race-free by construction).
// ============================================================================
__global__ __launch_bounds__(1024) void up_merged(
    const unsigned short* __restrict__ X,
    const unsigned short* __restrict__ WgT, const unsigned short* __restrict__ WuT,
    const unsigned short* __restrict__ WgsT, const unsigned short* __restrict__ WusT,
    unsigned short* __restrict__ HhT, unsigned short* __restrict__ HsT,
    const int* __restrict__ toklist, const int* __restrict__ counts) {
  const int KT = 64;
  bool sh; int e, nt, mt;
  if (!up_desc(counts, blockIdx.x, &sh, &e, &nt, &mt)) return;

  int cnt = sh ? T_TOK : counts[e];
  int m0 = mt * 256;
  if (m0 >= cnt) return;
  int n0 = nt * 128;
  int NS = sh ? (ISHARED >> 4) : (IMOE >> 4);
  int KTO = sh ? (ISHARED >> 5) : (IMOE >> 5);
  unsigned short* Hout = sh ? HsT : HhT;
  size_t hb = sh ? 0 : (size_t)e * (T_TOK >> 4);

  __shared__ unsigned short As[4][8192];
  __shared__ unsigned short Bgs[4][4096];
  __shared__ unsigned short Bus[4][4096];

  int tid = threadIdx.x, lane = tid & 63, wid = tid >> 6;
  int wm = wid >> 2, wn = wid & 3;
  int fr = lane & 15, fq = lane >> 4;

  int v = lane ^ ((lane >> 3) & 7);
  int rr = m0 + wid * 16 + (v >> 2);
  if (rr >= cnt) rr = cnt - 1;
  int tok = sh ? rr : toklist[e * T_TOK + rr];
  const unsigned short* aptr = X + (size_t)tok * H_DIM + ((v & 3) << 3);

  size_t nsg = (sh ? 0 : (size_t)e * NS) + (n0 >> 4) + (wid & 7);
  const unsigned short* bsrc =
      ((wid >> 3) ? (sh ? WusT : WuT) : (sh ? WgsT : WgT)) + nsg * KT * 512 + lane * 8;
  unsigned short* bdstBase = (wid >> 3) ? &Bus[0][0] : &Bgs[0][0];

  int fo = fr * 4 + fq;
  fo = (fo ^ ((fo >> 3) & 7)) * 8;

  f32x4 zero = {0.f, 0.f, 0.f, 0.f};
  f32x4 accg[4][2], accu[4][2];
#pragma unroll
  for (int i = 0; i < 4; i++)
#pragma unroll
    for (int jj = 0; jj < 2; jj++) { accg[i][jj] = zero; accu[i][jj] = zero; }

  auto stageA = [&](int b, int t) {
    gl16(aptr + (size_t)t * 32, &As[b][wid * 512]);
  };
  auto stageB = [&](int b, int t) {
    gl16(bsrc + (size_t)t * 512, bdstBase + b * 4096 + (wid & 7) * 512);
  };

  stageA(0, 0); stageB(0, 0);
  stageA(1, 1); stageB(1, 1);
  stageA(2, 2); stageB(2, 2);
  asm volatile("s_waitcnt vmcnt(4)" ::: "memory");
  __builtin_amdgcn_s_barrier();

  for (int t = 0; t < KT; ++t) {
    int b = t & 3;
    // ==== phase 1: af+bgf reads ∥ A-prefetch -> bar -> gate MFMAs -> bar ====
    bf16x8 af[4], bgf[2];
#pragma unroll
    for (int mi = 0; mi < 4; mi++)
      af[mi] = *(const bf16x8*)&As[b][(wm * 4 + mi) * 512 + fo];
#pragma unroll
    for (int ni = 0; ni < 2; ni++)
      bgf[ni] = *(const bf16x8*)&Bgs[b][(wn * 2 + ni) * 512 + fo];
    if (t + 3 < KT) stageA((t + 3) & 3, t + 3);
    __builtin_amdgcn_s_barrier();
    asm volatile("s_waitcnt lgkmcnt(0)" ::: "memory");
    __builtin_amdgcn_sched_barrier(0);
    __builtin_amdgcn_s_setprio(1);
#pragma unroll
    for (int mi = 0; mi < 4; mi++)
#pragma unroll
      for (int ni = 0; ni < 2; ni++)
        accg[mi][ni] = __builtin_amdgcn_mfma_f32_16x16x32_bf16(af[mi], bgf[ni], accg[mi][ni], 0, 0, 0);
    __builtin_amdgcn_s_setprio(0);
    __builtin_amdgcn_s_barrier();
    // ==== phase 2: buf reads ∥ B-prefetch -> vmcnt -> bar -> up MFMAs -> bar ====
    bf16x8 buf2[2];
#pragma unroll
    for (int ni = 0; ni < 2; ni++)
      buf2[ni] = *(const bf16x8*)&Bus[b][(wn * 2 + ni) * 512 + fo];
    if (t + 3 < KT) {
      stageB((t + 3) & 3, t + 3);
      asm volatile("s_waitcnt vmcnt(4)" ::: "memory");
    } else if (t + 2 < KT) {
      asm volatile("s_waitcnt vmcnt(2)" ::: "memory");
    } else if (t + 1 < KT) {
      asm volatile("s_waitcnt vmcnt(0)" ::: "memory");
    }
    __builtin_amdgcn_s_barrier();
    asm volatile("s_waitcnt lgkmcnt(0)" ::: "memory");
    __builtin_amdgcn_sched_barrier(0);
    __builtin_amdgcn_s_setprio(1);
#pragma unroll
    for (int mi = 0; mi < 4; mi++)
#pragma unroll
      for (int ni = 0; ni < 2; ni++)
        accu[mi][ni] = __builtin_amdgcn_mfma_f32_16x16x32_bf16(af[mi], buf2[ni], accu[mi][ni], 0, 0, 0);
    __builtin_amdgcn_s_setprio(0);
    __builtin_amdgcn_s_barrier();
  }

#pragma unroll
  for (int mi = 0; mi < 4; mi++) {
    int rb = m0 + wm * 64 + mi * 16;
    if (rb >= cnt) continue;
    int ms = rb >> 4;
#pragma unroll
    for (int ni = 0; ni < 2; ni++) {
      int col = n0 + wn * 32 + ni * 16 + fr;
      int kto = col >> 5;
      int c3 = (col >> 3) & 3;
      int jcol = col & 7;
      size_t base = ((hb + ms) * (size_t)KTO + kto) * 512 + jcol;
#pragma unroll
      for (int jj = 0; jj < 4; jj++) {
        int row = rb + fq * 4 + jj;
        if (row < cnt) {
          float g = accg[mi][ni][jj];
          float u = accu[mi][ni][jj];
          float h = g / (1.f + __expf(-g)) * u;
          int ul = (fq * 4 + jj) * 4 + c3;
          int ph = ul ^ ((ul >> 3) & 7);
          Hout[base + ph * 8] = f2bf(h);
        }
      }
    }
  }
}

// ============================================================================
// Merged down GEMM (round-15 verbatim): 8 waves, BM=128 BN=256, ring-3 72 KB
// -> 2 blk/CU, vmcnt(3)/(0) depth-2, shared K-split x2, inline descriptor map.
// ============================================================================
__global__ __launch_bounds__(512, 4) void down_merged(
    const unsigned short* __restrict__ HhT, const unsigned short* __restrict__ HsT,
    const unsigned short* __restrict__ WdT, const unsigned short* __restrict__ WdsT,
    float* __restrict__ Out,
    const int* __restrict__ toklist, const float* __restrict__ wts,
    const int* __restrict__ counts) {
  bool sh; int e, nt, mt, kc;
  if (!down_desc(counts, blockIdx.x, &sh, &e, &nt, &mt, &kc)) return;

  int cnt = sh ? T_TOK : counts[e];
  int m0 = mt * 128;
  if (m0 >= cnt) return;
  int n0 = nt * 256;
  int KTfull = sh ? (ISHARED >> 5) : (IMOE >> 5);
  int KT = sh ? 88 : 44;
  int koff = kc * 88;
  const int NS = H_DIM >> 4;

  __shared__ unsigned short As[3][4096];
  __shared__ unsigned short Bs[3][8192];

  int tid = threadIdx.x, lane = tid & 63, wid = tid >> 6;
  int wm = wid >> 2, wn = wid & 3;
  int fr = lane & 15, fq = lane >> 4;

  const unsigned short* Hin = sh ? HsT : HhT;
  size_t mbase = sh ? 0 : (size_t)e * (T_TOK >> 4);
  size_t ms = mbase + (m0 >> 4) + wid;
  const unsigned short* ap = Hin + ms * (size_t)KTfull * 512 + lane * 8;
  const unsigned short* WdBase = sh ? WdsT : WdT;
  size_t nsbase = (sh ? 0 : (size_t)e * NS) + (n0 >> 4);
  const unsigned short* bp0 = WdBase + (nsbase + wid * 2) * (size_t)KTfull * 512 + lane * 8;
  const unsigned short* bp1 = WdBase + (nsbase + wid * 2 + 1) * (size_t)KTfull * 512 + lane * 8;

  int fo = fr * 4 + fq;
  fo = (fo ^ ((fo >> 3) & 7)) * 8;

  f32x4 zero = {0.f, 0.f, 0.f, 0.f};
  f32x4 acc[4][4];
#pragma unroll
  for (int i = 0; i < 4; i++)
#pragma unroll
    for (int jj = 0; jj < 4; jj++) acc[i][jj] = zero;

  auto stage = [&](int b, int t) {
    gl16(ap + (size_t)(koff + t) * 512, &As[b][wid * 512]);
    gl16(bp0 + (size_t)(koff + t) * 512, &Bs[b][(wid * 2) * 512]);
    gl16(bp1 + (size_t)(koff + t) * 512, &Bs[b][(wid * 2 + 1) * 512]);
  };

  stage(0, 0);
  stage(1, 1);
  asm volatile("s_waitcnt vmcnt(3)" ::: "memory");
  __builtin_amdgcn_s_barrier();

  for (int t = 0; t < KT; ++t) {
    int b = t % 3;
    bf16x8 af[4], bf[4];
#pragma unroll
    for (int mi = 0; mi < 4; mi++)
      af[mi] = *(const bf16x8*)&As[b][(wm * 4 + mi) * 512 + fo];
#pragma unroll
    for (int ni = 0; ni < 4; ni++)
      bf[ni] = *(const bf16x8*)&Bs[b][(wn * 4 + ni) * 512 + fo];
    if (t + 2 < KT) {
      int nb = t + 2; nb %= 3;
      stage(nb, t + 2);
    }
    __builtin_amdgcn_s_setprio(1);
#pragma unroll
    for (int mi = 0; mi < 4; mi++)
#pragma unroll
      for (int ni = 0; ni < 4; ni++)
        acc[mi][ni] = __builtin_amdgcn_mfma_f32_16x16x32_bf16(af[mi], bf[ni], acc[mi][ni], 0, 0, 0);
    __builtin_amdgcn_s_setprio(0);
    if (t + 2 < KT) {
      asm volatile("s_waitcnt vmcnt(3)" ::: "memory");
      __builtin_amdgcn_s_barrier();
    } else if (t + 1 < KT) {
      asm volatile("s_waitcnt vmcnt(0)" ::: "memory");
      __builtin_amdgcn_s_barrier();
    }
  }

  int rbase = m0 + wm * 64;
  int cbase = n0 + wn * 64;
#pragma unroll
  for (int mi = 0; mi < 4; mi++)
#pragma unroll
    for (int ni = 0; ni < 4; ni++) {
      int col = cbase + ni * 16 + fr;
#pragma unroll
      for (int jj = 0; jj < 4; jj++) {
        int row = rbase + mi * 16 + fq * 4 + jj;
        if (row < cnt) {
          float vv = acc[mi][ni][jj];
          int tk;
          float wgt;
          if (sh) { tk = row; wgt = 1.0f; }
          else { tk = toklist[e * T_TOK + row]; wgt = wts[e * T_TOK + row]; }
          atomicAdd(&Out[(size_t)tk * H_DIM + col], wgt * vv);
        }
      }
    }
}

extern "C" void kernel_launch(void* const* d_in, const int* in_sizes, int n_in,
                              void* d_out, int out_size, void* d_ws, size_t ws_size,
                              hipStream_t stream) {
  const float* x = (const float*)d_in[0];
  const int* labels = (const int*)d_in[1];
  const float* cc = (const float*)d_in[2];
  const float* Wg = (const float*)d_in[3];
  const float* Wu = (const float*)d_in[4];
  const float* Wd = (const float*)d_in[5];
  const float* Wgs = (const float*)d_in[6];
  const float* Wus = (const float*)d_in[7];
  const float* Wds = (const float*)d_in[8];
  float* out = (float*)d_out;

  // ---- workspace layout ----
  uint8_t* p = (uint8_t*)d_ws;
  int* counts = (int*)p;            p += 256;
  int* toklist = (int*)p;           p += (size_t)NE * T_TOK * 4;
  float* wts = (float*)p;           p += (size_t)NE * T_TOK * 4;
  unsigned short* xbf = (unsigned short*)p;  p += (size_t)T_TOK * H_DIM * 2;
  unsigned short* WgT = (unsigned short*)p;  p += (size_t)NE * H_DIM * IMOE * 2;
  unsigned short* WuT = (unsigned short*)p;  p += (size_t)NE * H_DIM * IMOE * 2;
  unsigned short* WdT = (unsigned short*)p;  p += (size_t)NE * IMOE * H_DIM * 2;
  unsigned short* WgsT = (unsigned short*)p; p += (size_t)H_DIM * ISHARED * 2;
  unsigned short* WusT = (unsigned short*)p; p += (size_t)H_DIM * ISHARED * 2;
  unsigned short* WdsT = (unsigned short*)p; p += (size_t)ISHARED * H_DIM * 2;
  unsigned short* HhT = (unsigned short*)p;  p += (size_t)NE * T_TOK * IMOE * 2;
  unsigned short* HsT = (unsigned short*)p;  p += (size_t)T_TOK * ISHARED * 2;
  size_t need = (size_t)(p - (uint8_t*)d_ws);
  if (ws_size < need) return;  // fail visibly (harness validates output)

  hipMemsetAsync(d_ws, 0, 64, stream);
  hipMemsetAsync(d_out, 0, (size_t)out_size * 4, stream);

  prepass<<<59520, 256, 0, stream>>>(x, labels, cc, Wg, Wu, Wd, Wgs, Wus, Wds,
                                     xbf, counts, toklist, wts,
                                     WgT, WuT, WdT, WgsT, WusT, WdsT);

  up_merged<<<1144, 1024, 0, stream>>>(xbf, WgT, WuT, WgsT, WusT, HhT, HsT,
                                       toklist, counts);

  down_merged<<<1408, 512, 0, stream>>>(HhT, HsT, WdT, WdsT, out,
                                        toklist, wts, counts);
}

// Round 17
// 399.231 us; speedup vs baseline: 1.1708x; 1.1708x over previous
//
#include <hip/hip_runtime.h>
#include <hip/hip_bf16.h>
#include <stdint.h>

#define T_TOK 2048
#define H_DIM 2048
#define S_SEQ 1024
#define NE_ROUTED 8
#define NE 9
#define IMOE 1408
#define ISHARED 5632
#define UNCOND_LBL 1000

typedef short bf16x8 __attribute__((ext_vector_type(8)));
typedef float f32x4 __attribute__((ext_vector_type(4)));

__device__ __forceinline__ unsigned short f2bf(float f) {
  union { float f; unsigned int u; } v; v.f = f;
  unsigned int u = v.u;
  return (unsigned short)((u + 0x7fffu + ((u >> 16) & 1u)) >> 16);
}

__device__ __forceinline__ void gl16(const void* g, void* l) {
  __builtin_amdgcn_global_load_lds(
      (const __attribute__((address_space(1))) unsigned int*)g,
      (__attribute__((address_space(3))) unsigned int*)l, 16, 0, 0);
}

// ============================================================================
// Striped-swizzled bf16 layout: tensor[e][ns][kt][u][8], ns=n/16, kt=k/32,
// logical unit ul = (n&15)*4 + ((k>>3)&3), physical u = ul ^ ((ul>>3)&7).
// ============================================================================

__device__ __forceinline__ void transpose_body(
    const float* __restrict__ src, unsigned short* __restrict__ dst,
    int K, int N, int e, int kt, int n0, int t, float* tile /*[32][72]*/) {
  int NS = N >> 4, KT = K >> 5;
  const float* sp0 = src + (size_t)e * K * N + (size_t)kt * 32 * N + n0;
  int kr = t >> 3, nc = (t & 7) << 3;
  const float* sp = sp0 + (size_t)kr * N + nc;
  float4 a = *(const float4*)sp;
  float4 b = *(const float4*)(sp + 4);
  *(float4*)&tile[kr * 72 + nc] = a;
  *(float4*)&tile[kr * 72 + nc + 4] = b;
  __syncthreads();
  int nsl = t >> 6, up = t & 63;
  int ul = up ^ ((up >> 3) & 7);
  int rn = ul >> 2, fq = ul & 3;
  int nl = (nsl << 4) + rn;
  unsigned int pk[4];
#pragma unroll
  for (int j = 0; j < 4; j++) {
    float f0 = tile[(fq * 8 + 2 * j) * 72 + nl];
    float f1 = tile[(fq * 8 + 2 * j + 1) * 72 + nl];
    pk[j] = (unsigned)f2bf(f0) | ((unsigned)f2bf(f1) << 16);
  }
  size_t ns = (size_t)e * NS + (n0 >> 4) + nsl;
  unsigned short* dp = dst + (ns * KT + kt) * 512 + up * 8;
  *(uint4*)dp = make_uint4(pk[0], pk[1], pk[2], pk[3]);
}

// ============================================================================
// PREPASS: cvt(x->bf16) + router + all six weight transposes, ONE dispatch.
// ============================================================================
__global__ __launch_bounds__(256) void prepass(
    const float* __restrict__ x, const int* __restrict__ labels,
    const float* __restrict__ cc,
    const float* __restrict__ Wg, const float* __restrict__ Wu,
    const float* __restrict__ Wd, const float* __restrict__ Wgs,
    const float* __restrict__ Wus, const float* __restrict__ Wds,
    unsigned short* __restrict__ xbf,
    int* __restrict__ counts, int* __restrict__ toklist, float* __restrict__ wts,
    unsigned short* __restrict__ WgT, unsigned short* __restrict__ WuT,
    unsigned short* __restrict__ WdT, unsigned short* __restrict__ WgsT,
    unsigned short* __restrict__ WusT, unsigned short* __restrict__ WdsT) {
  __shared__ float tile[32 * 72];
  int blk = blockIdx.x;
  int tid = threadIdx.x;

  if (blk < 4096) {                       // ---- cvt ----
    int i = (blk * 256 + tid) * 4;
    float4 v = *(const float4*)(x + i);
    uint2 pk;
    pk.x = (unsigned)f2bf(v.x) | ((unsigned)f2bf(v.y) << 16);
    pk.y = (unsigned)f2bf(v.z) | ((unsigned)f2bf(v.w) << 16);
    *(uint2*)(xbf + i) = pk;
    return;
  }
  if (blk < 4608) {                       // ---- router ----
    int t = ((blk - 4096) * 256 + tid) >> 6;
    int lane = tid & 63;
    const float* xp = x + (size_t)t * H_DIM;
    float xx = 0.f;
    float d[NE_ROUTED], cn[NE_ROUTED];
#pragma unroll
    for (int e = 0; e < NE_ROUTED; e++) { d[e] = 0.f; cn[e] = 0.f; }
    for (int h = lane; h < H_DIM; h += 64) {
      float xv = xp[h];
      xx += xv * xv;
#pragma unroll
      for (int e = 0; e < NE_ROUTED; e++) {
        float cv = cc[e * H_DIM + h];
        d[e] += xv * cv;
        cn[e] += cv * cv;
      }
    }
#pragma unroll
    for (int off = 32; off > 0; off >>= 1) {
      xx += __shfl_xor(xx, off);
#pragma unroll
      for (int e = 0; e < NE_ROUTED; e++) {
        d[e] += __shfl_xor(d[e], off);
        cn[e] += __shfl_xor(cn[e], off);
      }
    }
    if (lane == 0) {
      int lab = labels[t / S_SEQ];
      if (lab == UNCOND_LBL) {
        int r = atomicAdd(&counts[NE - 1], 1);
        toklist[(NE - 1) * T_TOK + r] = t;
        wts[(NE - 1) * T_TOK + r] = 1.0f;
      } else {
        float xn = sqrtf(xx + 1e-12f);
        float cosv[NE_ROUTED];
        float mx = -1e30f;
#pragma unroll
        for (int e = 0; e < NE_ROUTED; e++) {
          cosv[e] = d[e] / (xn * sqrtf(cn[e] + 1e-12f));
          mx = fmaxf(mx, cosv[e]);
        }
        float p[NE_ROUTED];
        float s = 0.f;
#pragma unroll
        for (int e = 0; e < NE_ROUTED; e++) { p[e] = __expf(cosv[e] - mx); s += p[e]; }
        int i1 = 0;
#pragma unroll
        for (int e = 1; e < NE_ROUTED; e++) if (p[e] > p[i1]) i1 = e;
        int i2 = (i1 == 0) ? 1 : 0;
#pragma unroll
        for (int e = 0; e < NE_ROUTED; e++) if (e != i2 && e != i1 && p[e] > p[i2]) i2 = e;
        int r1 = atomicAdd(&counts[i1], 1);
        toklist[i1 * T_TOK + r1] = t;
        wts[i1 * T_TOK + r1] = p[i1] / s;
        int r2 = atomicAdd(&counts[i2], 1);
        toklist[i2 * T_TOK + r2] = t;
        wts[i2 * T_TOK + r2] = p[i2] / s;
      }
    }
    return;
  }
  int lid = blk - 4608;
  if (lid < 12672) {                       // Wg
    int e = lid / 1408, r = lid % 1408;
    int kt = r / 22, n0 = (r % 22) << 6;
    transpose_body(Wg, WgT, H_DIM, IMOE, e, kt, n0, tid, tile);
  } else if (lid < 25344) {                // Wu
    int r0 = lid - 12672;
    int e = r0 / 1408, r = r0 % 1408;
    int kt = r / 22, n0 = (r % 22) << 6;
    transpose_body(Wu, WuT, H_DIM, IMOE, e, kt, n0, tid, tile);
  } else if (lid < 38016) {                // Wd
    int r0 = lid - 25344;
    int e = r0 / 1408, r = r0 % 1408;
    int kt = r / 32, n0 = (r % 32) << 6;
    transpose_body(Wd, WdT, IMOE, H_DIM, e, kt, n0, tid, tile);
  } else if (lid < 43648) {                // Wgs
    int r = lid - 38016;
    int kt = r / 88, n0 = (r % 88) << 6;
    transpose_body(Wgs, WgsT, H_DIM, ISHARED, 0, kt, n0, tid, tile);
  } else if (lid < 49280) {                // Wus
    int r = lid - 43648;
    int kt = r / 88, n0 = (r % 88) << 6;
    transpose_body(Wus, WusT, H_DIM, ISHARED, 0, kt, n0, tid, tile);
  } else {                                 // Wds
    int r = lid - 49280;
    int kt = r / 32, n0 = (r % 32) << 6;
    transpose_body(Wds, WdsT, ISHARED, H_DIM, 0, kt, n0, tid, tile);
  }
}

// ---- inline descriptor lookup ----
// UP (BM=128, BN=128): [0,704) shared {nt<44, mt<16}; then routed
// {e, nt<11, mt<min(ceil(c/128),16)}, mt-fastest.
__device__ __forceinline__ bool up_desc(const int* counts, int d,
                                        bool* sh, int* e, int* nt, int* mt) {
  int mtm[NE];
  int nv = 704;
#pragma unroll
  for (int k = 0; k < NE; k++) {
    int c = counts[k];
    int m = (c + 127) >> 7; if (m > 16) m = 16;
    mtm[k] = m;
    nv += m * 11;
  }
  int q = nv >> 3, r = nv & 7;
  int x = d & 7, j = d >> 3;
  int cap = q + (x < r ? 1 : 0);
  if (j >= cap) return false;
  int idx = (x < r ? x * (q + 1) : r * (q + 1) + (x - r) * q) + j;
  if (idx < 704) {
    *sh = true; *e = 0; *nt = idx >> 4; *mt = idx & 15;
    return true;
  }
  idx -= 704;
#pragma unroll
  for (int k = 0; k < NE; k++) {
    int n = mtm[k] * 11;
    if (idx < n) {
      *sh = false; *e = k; *nt = idx / mtm[k]; *mt = idx % mtm[k];
      return true;
    }
    idx -= n;
  }
  return false;
}

__device__ __forceinline__ bool down_desc(const int* counts, int d,
                                          bool* sh, int* e, int* nt, int* mt, int* kc) {
  int x = d & 7, j = d >> 3;
  if (j < 32) {
    *sh = true; *e = 0; *nt = x; *mt = j >> 1; *kc = j & 1;
    return true;
  }
  int mtm[NE];
  int R = 0;
#pragma unroll
  for (int k = 0; k < NE; k++) {
    int c = counts[k];
    int m = (c + 127) >> 7; if (m > 16) m = 16;
    mtm[k] = m;
    R += m * 8;
  }
  int jr = j - 32;
  int q = R >> 3, r = R & 7;
  int cap = q + (x < r ? 1 : 0);
  if (jr >= cap) return false;
  int idx = (x < r ? x * (q + 1) : r * (q + 1) + (x - r) * q) + jr;
#pragma unroll
  for (int k = 0; k < NE; k++) {
    int n = mtm[k] * 8;
    if (idx < n) {
      *sh = false; *e = k; *nt = idx / mtm[k]; *mt = idx % mtm[k]; *kc = 0;
      return true;
    }
    idx -= n;
  }
  return false;
}

// ============================================================================
// Merged fused gate+up GEMM — 8-WAVE RETILE onto down_merged's proven
// skeleton: BM=128 BN=128 BK=32, ring-3 (72 KB -> 2 blk/CU at 4 waves/SIMD),
// 3 gl16/wave/step (A, Bg, Bu), counted vmcnt(3)/(0) depth-2, 2-phase MFMA
// (gate then up) with one barrier pair per K-step (round-15 sync discipline).
// ~1144 fine blocks over 512 slots kills the 1-blk/CU tail-idle (~48 us).
// ============================================================================
__global__ __launch_bounds__(512, 4) void up_merged(
    const unsigned short* __restrict__ X,
    const unsigned short* __restrict__ WgT, const unsigned short* __restrict__ WuT,
    const unsigned short* __restrict__ WgsT, const unsigned short* __restrict__ WusT,
    unsigned short* __restrict__ HhT, unsigned short* __restrict__ HsT,
    const int* __restrict__ toklist, const int* __restrict__ counts) {
  const int KT = 64;
  bool sh; int e, nt, mt;
  if (!up_desc(counts, blockIdx.x, &sh, &e, &nt, &mt)) return;

  int cnt = sh ? T_TOK : counts[e];
  int m0 = mt * 128;
  if (m0 >= cnt) return;
  int n0 = nt * 128;
  int NS = sh ? (ISHARED >> 4) : (IMOE >> 4);
  int KTO = sh ? (ISHARED >> 5) : (IMOE >> 5);
  unsigned short* Hout = sh ? HsT : HhT;
  size_t hb = sh ? 0 : (size_t)e * (T_TOK >> 4);

  __shared__ unsigned short As[3][4096];   // 8 subtiles x 512
  __shared__ unsigned short Bgs[3][4096];
  __shared__ unsigned short Bus[3][4096];

  int tid = threadIdx.x, lane = tid & 63, wid = tid >> 6;  // wid in [0,8)
  int wm = wid >> 2, wn = wid & 3;   // 2m x 4n, wave-tile 64x32
  int fr = lane & 15, fq = lane >> 4;

  // A gather: wave stages A-subtile wid (16 rows)
  int v = lane ^ ((lane >> 3) & 7);
  int rr = m0 + wid * 16 + (v >> 2);
  if (rr >= cnt) rr = cnt - 1;
  int tok = sh ? rr : toklist[e * T_TOK + rr];
  const unsigned short* aptr = X + (size_t)tok * H_DIM + ((v & 3) << 3);

  // B: wave stages subtile wid of BOTH gate and up tensors
  size_t nsg = (sh ? 0 : (size_t)e * NS) + (n0 >> 4) + wid;
  const unsigned short* bgp = (sh ? WgsT : WgT) + nsg * KT * 512 + lane * 8;
  const unsigned short* bup = (sh ? WusT : WuT) + nsg * KT * 512 + lane * 8;

  int fo = fr * 4 + fq;
  fo = (fo ^ ((fo >> 3) & 7)) * 8;

  f32x4 zero = {0.f, 0.f, 0.f, 0.f};
  f32x4 accg[4][2], accu[4][2];
#pragma unroll
  for (int i = 0; i < 4; i++)
#pragma unroll
    for (int jj = 0; jj < 2; jj++) { accg[i][jj] = zero; accu[i][jj] = zero; }

  auto stage = [&](int b, int t) {   // 3 loads/wave
    gl16(aptr + (size_t)t * 32, &As[b][wid * 512]);
    gl16(bgp + (size_t)t * 512, &Bgs[b][wid * 512]);
    gl16(bup + (size_t)t * 512, &Bus[b][wid * 512]);
  };

  stage(0, 0);
  stage(1, 1);
  asm volatile("s_waitcnt vmcnt(3)" ::: "memory");   // tile 0 landed
  __builtin_amdgcn_s_barrier();

  for (int t = 0; t < KT; ++t) {
    int b = t % 3;
    bf16x8 af[4], bgf[2], buf2[2];
#pragma unroll
    for (int mi = 0; mi < 4; mi++)
      af[mi] = *(const bf16x8*)&As[b][(wm * 4 + mi) * 512 + fo];
#pragma unroll
    for (int ni = 0; ni < 2; ni++) {
      bgf[ni] = *(const bf16x8*)&Bgs[b][(wn * 2 + ni) * 512 + fo];
      buf2[ni] = *(const bf16x8*)&Bus[b][(wn * 2 + ni) * 512 + fo];
    }
    if (t + 2 < KT) {
      int nb = t + 2; nb %= 3;
      stage(nb, t + 2);
    }
    __builtin_amdgcn_s_setprio(1);
#pragma unroll
    for (int mi = 0; mi < 4; mi++)
#pragma unroll
      for (int ni = 0; ni < 2; ni++) {
        accg[mi][ni] = __builtin_amdgcn_mfma_f32_16x16x32_bf16(af[mi], bgf[ni], accg[mi][ni], 0, 0, 0);
        accu[mi][ni] = __builtin_amdgcn_mfma_f32_16x16x32_bf16(af[mi], buf2[ni], accu[mi][ni], 0, 0, 0);
      }
    __builtin_amdgcn_s_setprio(0);
    if (t + 2 < KT) {
      asm volatile("s_waitcnt vmcnt(3)" ::: "memory");   // tile t+1 landed
      __builtin_amdgcn_s_barrier();
    } else if (t + 1 < KT) {
      asm volatile("s_waitcnt vmcnt(0)" ::: "memory");
      __builtin_amdgcn_s_barrier();
    }
  }

  // epilogue: silu(g)*u -> bf16, striped Hout
#pragma unroll
  for (int mi = 0; mi < 4; mi++) {
    int rb = m0 + wm * 64 + mi * 16;
    if (rb >= cnt) continue;
    int ms = rb >> 4;
#pragma unroll
    for (int ni = 0; ni < 2; ni++) {
      int col = n0 + wn * 32 + ni * 16 + fr;
      int kto = col >> 5;
      int c3 = (col >> 3) & 3;
      int jcol = col & 7;
      size_t base = ((hb + ms) * (size_t)KTO + kto) * 512 + jcol;
#pragma unroll
      for (int jj = 0; jj < 4; jj++) {
        int row = rb + fq * 4 + jj;
        if (row < cnt) {
          float g = accg[mi][ni][jj];
          float u = accu[mi][ni][jj];
          float h = g / (1.f + __expf(-g)) * u;
          int ul = (fq * 4 + jj) * 4 + c3;
          int ph = ul ^ ((ul >> 3) & 7);
          Hout[base + ph * 8] = f2bf(h);
        }
      }
    }
  }
}

// ============================================================================
// Merged down GEMM (round-15 verbatim): 8 waves, BM=128 BN=256, ring-3 72 KB
// -> 2 blk/CU, vmcnt(3)/(0) depth-2, shared K-split x2, inline descriptor map.
// ============================================================================
__global__ __launch_bounds__(512, 4) void down_merged(
    const unsigned short* __restrict__ HhT, const unsigned short* __restrict__ HsT,
    const unsigned short* __restrict__ WdT, const unsigned short* __restrict__ WdsT,
    float* __restrict__ Out,
    const int* __restrict__ toklist, const float* __restrict__ wts,
    const int* __restrict__ counts) {
  bool sh; int e, nt, mt, kc;
  if (!down_desc(counts, blockIdx.x, &sh, &e, &nt, &mt, &kc)) return;

  int cnt = sh ? T_TOK : counts[e];
  int m0 = mt * 128;
  if (m0 >= cnt) return;
  int n0 = nt * 256;
  int KTfull = sh ? (ISHARED >> 5) : (IMOE >> 5);
  int KT = sh ? 88 : 44;
  int koff = kc * 88;
  const int NS = H_DIM >> 4;

  __shared__ unsigned short As[3][4096];
  __shared__ unsigned short Bs[3][8192];

  int tid = threadIdx.x, lane = tid & 63, wid = tid >> 6;
  int wm = wid >> 2, wn = wid & 3;
  int fr = lane & 15, fq = lane >> 4;

  const unsigned short* Hin = sh ? HsT : HhT;
  size_t mbase = sh ? 0 : (size_t)e * (T_TOK >> 4);
  size_t ms = mbase + (m0 >> 4) + wid;
  const unsigned short* ap = Hin + ms * (size_t)KTfull * 512 + lane * 8;
  const unsigned short* WdBase = sh ? WdsT : WdT;
  size_t nsbase = (sh ? 0 : (size_t)e * NS) + (n0 >> 4);
  const unsigned short* bp0 = WdBase + (nsbase + wid * 2) * (size_t)KTfull * 512 + lane * 8;
  const unsigned short* bp1 = WdBase + (nsbase + wid * 2 + 1) * (size_t)KTfull * 512 + lane * 8;

  int fo = fr * 4 + fq;
  fo = (fo ^ ((fo >> 3) & 7)) * 8;

  f32x4 zero = {0.f, 0.f, 0.f, 0.f};
  f32x4 acc[4][4];
#pragma unroll
  for (int i = 0; i < 4; i++)
#pragma unroll
    for (int jj = 0; jj < 4; jj++) acc[i][jj] = zero;

  auto stage = [&](int b, int t) {
    gl16(ap + (size_t)(koff + t) * 512, &As[b][wid * 512]);
    gl16(bp0 + (size_t)(koff + t) * 512, &Bs[b][(wid * 2) * 512]);
    gl16(bp1 + (size_t)(koff + t) * 512, &Bs[b][(wid * 2 + 1) * 512]);
  };

  stage(0, 0);
  stage(1, 1);
  asm volatile("s_waitcnt vmcnt(3)" ::: "memory");
  __builtin_amdgcn_s_barrier();

  for (int t = 0; t < KT; ++t) {
    int b = t % 3;
    bf16x8 af[4], bf[4];
#pragma unroll
    for (int mi = 0; mi < 4; mi++)
      af[mi] = *(const bf16x8*)&As[b][(wm * 4 + mi) * 512 + fo];
#pragma unroll
    for (int ni = 0; ni < 4; ni++)
      bf[ni] = *(const bf16x8*)&Bs[b][(wn * 4 + ni) * 512 + fo];
    if (t + 2 < KT) {
      int nb = t + 2; nb %= 3;
      stage(nb, t + 2);
    }
    __builtin_amdgcn_s_setprio(1);
#pragma unroll
    for (int mi = 0; mi < 4; mi++)
#pragma unroll
      for (int ni = 0; ni < 4; ni++)
        acc[mi][ni] = __builtin_amdgcn_mfma_f32_16x16x32_bf16(af[mi], bf[ni], acc[mi][ni], 0, 0, 0);
    __builtin_amdgcn_s_setprio(0);
    if (t + 2 < KT) {
      asm volatile("s_waitcnt vmcnt(3)" ::: "memory");
      __builtin_amdgcn_s_barrier();
    } else if (t + 1 < KT) {
      asm volatile("s_waitcnt vmcnt(0)" ::: "memory");
      __builtin_amdgcn_s_barrier();
    }
  }

  int rbase = m0 + wm * 64;
  int cbase = n0 + wn * 64;
#pragma unroll
  for (int mi = 0; mi < 4; mi++)
#pragma unroll
    for (int ni = 0; ni < 4; ni++) {
      int col = cbase + ni * 16 + fr;
#pragma unroll
      for (int jj = 0; jj < 4; jj++) {
        int row = rbase + mi * 16 + fq * 4 + jj;
        if (row < cnt) {
          float vv = acc[mi][ni][jj];
          int tk;
          float wgt;
          if (sh) { tk = row; wgt = 1.0f; }
          else { tk = toklist[e * T_TOK + row]; wgt = wts[e * T_TOK + row]; }
          atomicAdd(&Out[(size_t)tk * H_DIM + col], wgt * vv);
        }
      }
    }
}

extern "C" void kernel_launch(void* const* d_in, const int* in_sizes, int n_in,
                              void* d_out, int out_size, void* d_ws, size_t ws_size,
                              hipStream_t stream) {
  const float* x = (const float*)d_in[0];
  const int* labels = (const int*)d_in[1];
  const float* cc = (const float*)d_in[2];
  const float* Wg = (const float*)d_in[3];
  const float* Wu = (const float*)d_in[4];
  const float* Wd = (const float*)d_in[5];
  const float* Wgs = (const float*)d_in[6];
  const float* Wus = (const float*)d_in[7];
  const float* Wds = (const float*)d_in[8];
  float* out = (float*)d_out;

  // ---- workspace layout ----
  uint8_t* p = (uint8_t*)d_ws;
  int* counts = (int*)p;            p += 256;
  int* toklist = (int*)p;           p += (size_t)NE * T_TOK * 4;
  float* wts = (float*)p;           p += (size_t)NE * T_TOK * 4;
  unsigned short* xbf = (unsigned short*)p;  p += (size_t)T_TOK * H_DIM * 2;
  unsigned short* WgT = (unsigned short*)p;  p += (size_t)NE * H_DIM * IMOE * 2;
  unsigned short* WuT = (unsigned short*)p;  p += (size_t)NE * H_DIM * IMOE * 2;
  unsigned short* WdT = (unsigned short*)p;  p += (size_t)NE * IMOE * H_DIM * 2;
  unsigned short* WgsT = (unsigned short*)p; p += (size_t)H_DIM * ISHARED * 2;
  unsigned short* WusT = (unsigned short*)p; p += (size_t)H_DIM * ISHARED * 2;
  unsigned short* WdsT = (unsigned short*)p; p += (size_t)ISHARED * H_DIM * 2;
  unsigned short* HhT = (unsigned short*)p;  p += (size_t)NE * T_TOK * IMOE * 2;
  unsigned short* HsT = (unsigned short*)p;  p += (size_t)T_TOK * ISHARED * 2;
  size_t need = (size_t)(p - (uint8_t*)d_ws);
  if (ws_size < need) return;  // fail visibly (harness validates output)

  hipMemsetAsync(d_ws, 0, 64, stream);
  hipMemsetAsync(d_out, 0, (size_t)out_size * 4, stream);

  prepass<<<59520, 256, 0, stream>>>(x, labels, cc, Wg, Wu, Wd, Wgs, Wus, Wds,
                                     xbf, counts, toklist, wts,
                                     WgT, WuT, WdT, WgsT, WusT, WdsT);

  // worst case: 704 shared + 9*16*11 = 1584 routed -> 2288; inactive exit
  up_merged<<<2288, 512, 0, stream>>>(xbf, WgT, WuT, WgsT, WusT, HhT, HsT,
                                      toklist, counts);

  down_merged<<<1408, 512, 0, stream>>>(HhT, HsT, WdT, WdsT, out,
                                        toklist, wts, counts);
}

// Round 18
// 398.263 us; speedup vs baseline: 1.1736x; 1.0024x over previous
//
#include <hip/hip_runtime.h>
#include <hip/hip_bf16.h>
#include <stdint.h>

#define T_TOK 2048
#define H_DIM 2048
#define S_SEQ 1024
#define NE_ROUTED 8
#define NE 9
#define IMOE 1408
#define ISHARED 5632
#define UNCOND_LBL 1000

typedef short bf16x8 __attribute__((ext_vector_type(8)));
typedef float f32x4 __attribute__((ext_vector_type(4)));

__device__ __forceinline__ unsigned short f2bf(float f) {
  union { float f; unsigned int u; } v; v.f = f;
  unsigned int u = v.u;
  return (unsigned short)((u + 0x7fffu + ((u >> 16) & 1u)) >> 16);
}

__device__ __forceinline__ void gl16(const void* g, void* l) {
  __builtin_amdgcn_global_load_lds(
      (const __attribute__((address_space(1))) unsigned int*)g,
      (__attribute__((address_space(3))) unsigned int*)l, 16, 0, 0);
}

// ============================================================================
// Striped-swizzled bf16 layout: tensor[e][ns][kt][u][8], ns=n/16, kt=k/32,
// logical unit ul = (n&15)*4 + ((k>>3)&3), physical u = ul ^ ((ul>>3)&7).
// ============================================================================

// LDS tile stride 73 (odd): write banks (73*kr+8c) mod 32 spread ~2-way (was
// 16-way at stride 72: 8*(9kr+c) mod 32 in {0,8,16,24}); read banks
// (8fq+18j+nl) mod 32 exactly 2-way (free, m136).
#define TS 73

__device__ __forceinline__ void transpose_body(
    const float* __restrict__ src, unsigned short* __restrict__ dst,
    int K, int N, int e, int kt, int n0, int t, float* tile /*[32][TS]*/) {
  int NS = N >> 4, KT = K >> 5;
  const float* sp0 = src + (size_t)e * K * N + (size_t)kt * 32 * N + n0;
  int kr = t >> 3, nc = (t & 7) << 3;
  const float* sp = sp0 + (size_t)kr * N + nc;
  float4 a = *(const float4*)sp;
  float4 b = *(const float4*)(sp + 4);
  *(float4*)&tile[kr * TS + nc] = a;
  *(float4*)&tile[kr * TS + nc + 4] = b;
  __syncthreads();
  int nsl = t >> 6, up = t & 63;
  int ul = up ^ ((up >> 3) & 7);
  int rn = ul >> 2, fq = ul & 3;
  int nl = (nsl << 4) + rn;
  unsigned int pk[4];
#pragma unroll
  for (int j = 0; j < 4; j++) {
    float f0 = tile[(fq * 8 + 2 * j) * TS + nl];
    float f1 = tile[(fq * 8 + 2 * j + 1) * TS + nl];
    pk[j] = (unsigned)f2bf(f0) | ((unsigned)f2bf(f1) << 16);
  }
  size_t ns = (size_t)e * NS + (n0 >> 4) + nsl;
  unsigned short* dp = dst + (ns * KT + kt) * 512 + up * 8;
  *(uint4*)dp = make_uint4(pk[0], pk[1], pk[2], pk[3]);
}

// ============================================================================
// PREPASS: cvt(x->bf16) + router + all six weight transposes, ONE dispatch.
// ============================================================================
__global__ __launch_bounds__(256) void prepass(
    const float* __restrict__ x, const int* __restrict__ labels,
    const float* __restrict__ cc,
    const float* __restrict__ Wg, const float* __restrict__ Wu,
    const float* __restrict__ Wd, const float* __restrict__ Wgs,
    const float* __restrict__ Wus, const float* __restrict__ Wds,
    unsigned short* __restrict__ xbf,
    int* __restrict__ counts, int* __restrict__ toklist, float* __restrict__ wts,
    unsigned short* __restrict__ WgT, unsigned short* __restrict__ WuT,
    unsigned short* __restrict__ WdT, unsigned short* __restrict__ WgsT,
    unsigned short* __restrict__ WusT, unsigned short* __restrict__ WdsT) {
  __shared__ float tile[32 * TS];
  int blk = blockIdx.x;
  int tid = threadIdx.x;

  if (blk < 4096) {                       // ---- cvt ----
    int i = (blk * 256 + tid) * 4;
    float4 v = *(const float4*)(x + i);
    uint2 pk;
    pk.x = (unsigned)f2bf(v.x) | ((unsigned)f2bf(v.y) << 16);
    pk.y = (unsigned)f2bf(v.z) | ((unsigned)f2bf(v.w) << 16);
    *(uint2*)(xbf + i) = pk;
    return;
  }
  if (blk < 4608) {                       // ---- router ----
    int t = ((blk - 4096) * 256 + tid) >> 6;
    int lane = tid & 63;
    const float* xp = x + (size_t)t * H_DIM;
    float xx = 0.f;
    float d[NE_ROUTED], cn[NE_ROUTED];
#pragma unroll
    for (int e = 0; e < NE_ROUTED; e++) { d[e] = 0.f; cn[e] = 0.f; }
    for (int h = lane; h < H_DIM; h += 64) {
      float xv = xp[h];
      xx += xv * xv;
#pragma unroll
      for (int e = 0; e < NE_ROUTED; e++) {
        float cv = cc[e * H_DIM + h];
        d[e] += xv * cv;
        cn[e] += cv * cv;
      }
    }
#pragma unroll
    for (int off = 32; off > 0; off >>= 1) {
      xx += __shfl_xor(xx, off);
#pragma unroll
      for (int e = 0; e < NE_ROUTED; e++) {
        d[e] += __shfl_xor(d[e], off);
        cn[e] += __shfl_xor(cn[e], off);
      }
    }
    if (lane == 0) {
      int lab = labels[t / S_SEQ];
      if (lab == UNCOND_LBL) {
        int r = atomicAdd(&counts[NE - 1], 1);
        toklist[(NE - 1) * T_TOK + r] = t;
        wts[(NE - 1) * T_TOK + r] = 1.0f;
      } else {
        float xn = sqrtf(xx + 1e-12f);
        float cosv[NE_ROUTED];
        float mx = -1e30f;
#pragma unroll
        for (int e = 0; e < NE_ROUTED; e++) {
          cosv[e] = d[e] / (xn * sqrtf(cn[e] + 1e-12f));
          mx = fmaxf(mx, cosv[e]);
        }
        float p[NE_ROUTED];
        float s = 0.f;
#pragma unroll
        for (int e = 0; e < NE_ROUTED; e++) { p[e] = __expf(cosv[e] - mx); s += p[e]; }
        int i1 = 0;
#pragma unroll
        for (int e = 1; e < NE_ROUTED; e++) if (p[e] > p[i1]) i1 = e;
        int i2 = (i1 == 0) ? 1 : 0;
#pragma unroll
        for (int e = 0; e < NE_ROUTED; e++) if (e != i2 && e != i1 && p[e] > p[i2]) i2 = e;
        int r1 = atomicAdd(&counts[i1], 1);
        toklist[i1 * T_TOK + r1] = t;
        wts[i1 * T_TOK + r1] = p[i1] / s;
        int r2 = atomicAdd(&counts[i2], 1);
        toklist[i2 * T_TOK + r2] = t;
        wts[i2 * T_TOK + r2] = p[i2] / s;
      }
    }
    return;
  }
  int lid = blk - 4608;
  if (lid < 12672) {                       // Wg
    int e = lid / 1408, r = lid % 1408;
    int kt = r / 22, n0 = (r % 22) << 6;
    transpose_body(Wg, WgT, H_DIM, IMOE, e, kt, n0, tid, tile);
  } else if (lid < 25344) {                // Wu
    int r0 = lid - 12672;
    int e = r0 / 1408, r = r0 % 1408;
    int kt = r / 22, n0 = (r % 22) << 6;
    transpose_body(Wu, WuT, H_DIM, IMOE, e, kt, n0, tid, tile);
  } else if (lid < 38016) {                // Wd
    int r0 = lid - 25344;
    int e = r0 / 1408, r = r0 % 1408;
    int kt = r / 32, n0 = (r % 32) << 6;
    transpose_body(Wd, WdT, IMOE, H_DIM, e, kt, n0, tid, tile);
  } else if (lid < 43648) {                // Wgs
    int r = lid - 38016;
    int kt = r / 88, n0 = (r % 88) << 6;
    transpose_body(Wgs, WgsT, H_DIM, ISHARED, 0, kt, n0, tid, tile);
  } else if (lid < 49280) {                // Wus
    int r = lid - 43648;
    int kt = r / 88, n0 = (r % 88) << 6;
    transpose_body(Wus, WusT, H_DIM, ISHARED, 0, kt, n0, tid, tile);
  } else {                                 // Wds
    int r = lid - 49280;
    int kt = r / 32, n0 = (r % 32) << 6;
    transpose_body(Wds, WdsT, ISHARED, H_DIM, 0, kt, n0, tid, tile);
  }
}

// ---- inline descriptor lookup ----
__device__ __forceinline__ bool up_desc(const int* counts, int d,
                                        bool* sh, int* e, int* nt, int* mt) {
  int mtm[NE];
  int nv = 704;
#pragma unroll
  for (int k = 0; k < NE; k++) {
    int c = counts[k];
    int m = (c + 127) >> 7; if (m > 16) m = 16;
    mtm[k] = m;
    nv += m * 11;
  }
  int q = nv >> 3, r = nv & 7;
  int x = d & 7, j = d >> 3;
  int cap = q + (x < r ? 1 : 0);
  if (j >= cap) return false;
  int idx = (x < r ? x * (q + 1) : r * (q + 1) + (x - r) * q) + j;
  if (idx < 704) {
    *sh = true; *e = 0; *nt = idx >> 4; *mt = idx & 15;
    return true;
  }
  idx -= 704;
#pragma unroll
  for (int k = 0; k < NE; k++) {
    int n = mtm[k] * 11;
    if (idx < n) {
      *sh = false; *e = k; *nt = idx / mtm[k]; *mt = idx % mtm[k];
      return true;
    }
    idx -= n;
  }
  return false;
}

__device__ __forceinline__ bool down_desc(const int* counts, int d,
                                          bool* sh, int* e, int* nt, int* mt, int* kc) {
  int x = d & 7, j = d >> 3;
  if (j < 32) {
    *sh = true; *e = 0; *nt = x; *mt = j >> 1; *kc = j & 1;
    return true;
  }
  int mtm[NE];
  int R = 0;
#pragma unroll
  for (int k = 0; k < NE; k++) {
    int c = counts[k];
    int m = (c + 127) >> 7; if (m > 16) m = 16;
    mtm[k] = m;
    R += m * 8;
  }
  int jr = j - 32;
  int q = R >> 3, r = R & 7;
  int cap = q + (x < r ? 1 : 0);
  if (jr >= cap) return false;
  int idx = (x < r ? x * (q + 1) : r * (q + 1) + (x - r) * q) + jr;
#pragma unroll
  for (int k = 0; k < NE; k++) {
    int n = mtm[k] * 8;
    if (idx < n) {
      *sh = false; *e = k; *nt = idx / mtm[k]; *mt = idx % mtm[k]; *kc = 0;
      return true;
    }
    idx -= n;
  }
  return false;
}

// ============================================================================
// Merged fused gate+up GEMM (round-17 verbatim): 8 waves, BM=128 BN=128,
// ring-3 (72 KB -> 2 blk/CU), 3 gl16/wave/step, vmcnt(3)/(0) depth-2.
// ============================================================================
__global__ __launch_bounds__(512, 4) void up_merged(
    const unsigned short* __restrict__ X,
    const unsigned short* __restrict__ WgT, const unsigned short* __restrict__ WuT,
    const unsigned short* __restrict__ WgsT, const unsigned short* __restrict__ WusT,
    unsigned short* __restrict__ HhT, unsigned short* __restrict__ HsT,
    const int* __restrict__ toklist, const int* __restrict__ counts) {
  const int KT = 64;
  bool sh; int e, nt, mt;
  if (!up_desc(counts, blockIdx.x, &sh, &e, &nt, &mt)) return;

  int cnt = sh ? T_TOK : counts[e];
  int m0 = mt * 128;
  if (m0 >= cnt) return;
  int n0 = nt * 128;
  int NS = sh ? (ISHARED >> 4) : (IMOE >> 4);
  int KTO = sh ? (ISHARED >> 5) : (IMOE >> 5);
  unsigned short* Hout = sh ? HsT : HhT;
  size_t hb = sh ? 0 : (size_t)e * (T_TOK >> 4);

  __shared__ unsigned short As[3][4096];
  __shared__ unsigned short Bgs[3][4096];
  __shared__ unsigned short Bus[3][4096];

  int tid = threadIdx.x, lane = tid & 63, wid = tid >> 6;
  int wm = wid >> 2, wn = wid & 3;
  int fr = lane & 15, fq = lane >> 4;

  int v = lane ^ ((lane >> 3) & 7);
  int rr = m0 + wid * 16 + (v >> 2);
  if (rr >= cnt) rr = cnt - 1;
  int tok = sh ? rr : toklist[e * T_TOK + rr];
  const unsigned short* aptr = X + (size_t)tok * H_DIM + ((v & 3) << 3);

  size_t nsg = (sh ? 0 : (size_t)e * NS) + (n0 >> 4) + wid;
  const unsigned short* bgp = (sh ? WgsT : WgT) + nsg * KT * 512 + lane * 8;
  const unsigned short* bup = (sh ? WusT : WuT) + nsg * KT * 512 + lane * 8;

  int fo = fr * 4 + fq;
  fo = (fo ^ ((fo >> 3) & 7)) * 8;

  f32x4 zero = {0.f, 0.f, 0.f, 0.f};
  f32x4 accg[4][2], accu[4][2];
#pragma unroll
  for (int i = 0; i < 4; i++)
#pragma unroll
    for (int jj = 0; jj < 2; jj++) { accg[i][jj] = zero; accu[i][jj] = zero; }

  auto stage = [&](int b, int t) {
    gl16(aptr + (size_t)t * 32, &As[b][wid * 512]);
    gl16(bgp + (size_t)t * 512, &Bgs[b][wid * 512]);
    gl16(bup + (size_t)t * 512, &Bus[b][wid * 512]);
  };

  stage(0, 0);
  stage(1, 1);
  asm volatile("s_waitcnt vmcnt(3)" ::: "memory");
  __builtin_amdgcn_s_barrier();

  for (int t = 0; t < KT; ++t) {
    int b = t % 3;
    bf16x8 af[4], bgf[2], buf2[2];
#pragma unroll
    for (int mi = 0; mi < 4; mi++)
      af[mi] = *(const bf16x8*)&As[b][(wm * 4 + mi) * 512 + fo];
#pragma unroll
    for (int ni = 0; ni < 2; ni++) {
      bgf[ni] = *(const bf16x8*)&Bgs[b][(wn * 2 + ni) * 512 + fo];
      buf2[ni] = *(const bf16x8*)&Bus[b][(wn * 2 + ni) * 512 + fo];
    }
    if (t + 2 < KT) {
      int nb = t + 2; nb %= 3;
      stage(nb, t + 2);
    }
    __builtin_amdgcn_s_setprio(1);
#pragma unroll
    for (int mi = 0; mi < 4; mi++)
#pragma unroll
      for (int ni = 0; ni < 2; ni++) {
        accg[mi][ni] = __builtin_amdgcn_mfma_f32_16x16x32_bf16(af[mi], bgf[ni], accg[mi][ni], 0, 0, 0);
        accu[mi][ni] = __builtin_amdgcn_mfma_f32_16x16x32_bf16(af[mi], buf2[ni], accu[mi][ni], 0, 0, 0);
      }
    __builtin_amdgcn_s_setprio(0);
    if (t + 2 < KT) {
      asm volatile("s_waitcnt vmcnt(3)" ::: "memory");
      __builtin_amdgcn_s_barrier();
    } else if (t + 1 < KT) {
      asm volatile("s_waitcnt vmcnt(0)" ::: "memory");
      __builtin_amdgcn_s_barrier();
    }
  }

#pragma unroll
  for (int mi = 0; mi < 4; mi++) {
    int rb = m0 + wm * 64 + mi * 16;
    if (rb >= cnt) continue;
    int ms = rb >> 4;
#pragma unroll
    for (int ni = 0; ni < 2; ni++) {
      int col = n0 + wn * 32 + ni * 16 + fr;
      int kto = col >> 5;
      int c3 = (col >> 3) & 3;
      int jcol = col & 7;
      size_t base = ((hb + ms) * (size_t)KTO + kto) * 512 + jcol;
#pragma unroll
      for (int jj = 0; jj < 4; jj++) {
        int row = rb + fq * 4 + jj;
        if (row < cnt) {
          float g = accg[mi][ni][jj];
          float u = accu[mi][ni][jj];
          float h = g / (1.f + __expf(-g)) * u;
          int ul = (fq * 4 + jj) * 4 + c3;
          int ph = ul ^ ((ul >> 3) & 7);
          Hout[base + ph * 8] = f2bf(h);
        }
      }
    }
  }
}

// ============================================================================
// Merged down GEMM (round-17 verbatim): 8 waves, BM=128 BN=256, ring-3 72 KB
// -> 2 blk/CU, vmcnt(3)/(0) depth-2, shared K-split x2, inline descriptor map.
// ============================================================================
__global__ __launch_bounds__(512, 4) void down_merged(
    const unsigned short* __restrict__ HhT, const unsigned short* __restrict__ HsT,
    const unsigned short* __restrict__ WdT, const unsigned short* __restrict__ WdsT,
    float* __restrict__ Out,
    const int* __restrict__ toklist, const float* __restrict__ wts,
    const int* __restrict__ counts) {
  bool sh; int e, nt, mt, kc;
  if (!down_desc(counts, blockIdx.x, &sh, &e, &nt, &mt, &kc)) return;

  int cnt = sh ? T_TOK : counts[e];
  int m0 = mt * 128;
  if (m0 >= cnt) return;
  int n0 = nt * 256;
  int KTfull = sh ? (ISHARED >> 5) : (IMOE >> 5);
  int KT = sh ? 88 : 44;
  int koff = kc * 88;
  const int NS = H_DIM >> 4;

  __shared__ unsigned short As[3][4096];
  __shared__ unsigned short Bs[3][8192];

  int tid = threadIdx.x, lane = tid & 63, wid = tid >> 6;
  int wm = wid >> 2, wn = wid & 3;
  int fr = lane & 15, fq = lane >> 4;

  const unsigned short* Hin = sh ? HsT : HhT;
  size_t mbase = sh ? 0 : (size_t)e * (T_TOK >> 4);
  size_t ms = mbase + (m0 >> 4) + wid;
  const unsigned short* ap = Hin + ms * (size_t)KTfull * 512 + lane * 8;
  const unsigned short* WdBase = sh ? WdsT : WdT;
  size_t nsbase = (sh ? 0 : (size_t)e * NS) + (n0 >> 4);
  const unsigned short* bp0 = WdBase + (nsbase + wid * 2) * (size_t)KTfull * 512 + lane * 8;
  const unsigned short* bp1 = WdBase + (nsbase + wid * 2 + 1) * (size_t)KTfull * 512 + lane * 8;

  int fo = fr * 4 + fq;
  fo = (fo ^ ((fo >> 3) & 7)) * 8;

  f32x4 zero = {0.f, 0.f, 0.f, 0.f};
  f32x4 acc[4][4];
#pragma unroll
  for (int i = 0; i < 4; i++)
#pragma unroll
    for (int jj = 0; jj < 4; jj++) acc[i][jj] = zero;

  auto stage = [&](int b, int t) {
    gl16(ap + (size_t)(koff + t) * 512, &As[b][wid * 512]);
    gl16(bp0 + (size_t)(koff + t) * 512, &Bs[b][(wid * 2) * 512]);
    gl16(bp1 + (size_t)(koff + t) * 512, &Bs[b][(wid * 2 + 1) * 512]);
  };

  stage(0, 0);
  stage(1, 1);
  asm volatile("s_waitcnt vmcnt(3)" ::: "memory");
  __builtin_amdgcn_s_barrier();

  for (int t = 0; t < KT; ++t) {
    int b = t % 3;
    bf16x8 af[4], bf[4];
#pragma unroll
    for (int mi = 0; mi < 4; mi++)
      af[mi] = *(const bf16x8*)&As[b][(wm * 4 + mi) * 512 + fo];
#pragma unroll
    for (int ni = 0; ni < 4; ni++)
      bf[ni] = *(const bf16x8*)&Bs[b][(wn * 4 + ni) * 512 + fo];
    if (t + 2 < KT) {
      int nb = t + 2; nb %= 3;
      stage(nb, t + 2);
    }
    __builtin_amdgcn_s_setprio(1);
#pragma unroll
    for (int mi = 0; mi < 4; mi++)
#pragma unroll
      for (int ni = 0; ni < 4; ni++)
        acc[mi][ni] = __builtin_amdgcn_mfma_f32_16x16x32_bf16(af[mi], bf[ni], acc[mi][ni], 0, 0, 0);
    __builtin_amdgcn_s_setprio(0);
    if (t + 2 < KT) {
      asm volatile("s_waitcnt vmcnt(3)" ::: "memory");
      __builtin_amdgcn_s_barrier();
    } else if (t + 1 < KT) {
      asm volatile("s_waitcnt vmcnt(0)" ::: "memory");
      __builtin_amdgcn_s_barrier();
    }
  }

  int rbase = m0 + wm * 64;
  int cbase = n0 + wn * 64;
#pragma unroll
  for (int mi = 0; mi < 4; mi++)
#pragma unroll
    for (int ni = 0; ni < 4; ni++) {
      int col = cbase + ni * 16 + fr;
#pragma unroll
      for (int jj = 0; jj < 4; jj++) {
        int row = rbase + mi * 16 + fq * 4 + jj;
        if (row < cnt) {
          float vv = acc[mi][ni][jj];
          int tk;
          float wgt;
          if (sh) { tk = row; wgt = 1.0f; }
          else { tk = toklist[e * T_TOK + row]; wgt = wts[e * T_TOK + row]; }
          atomicAdd(&Out[(size_t)tk * H_DIM + col], wgt * vv);
        }
      }
    }
}

extern "C" void kernel_launch(void* const* d_in, const int* in_sizes, int n_in,
                              void* d_out, int out_size, void* d_ws, size_t ws_size,
                              hipStream_t stream) {
  const float* x = (const float*)d_in[0];
  const int* labels = (const int*)d_in[1];
  const float* cc = (const float*)d_in[2];
  const float* Wg = (const float*)d_in[3];
  const float* Wu = (const float*)d_in[4];
  const float* Wd = (const float*)d_in[5];
  const float* Wgs = (const float*)d_in[6];
  const float* Wus = (const float*)d_in[7];
  const float* Wds = (const float*)d_in[8];
  float* out = (float*)d_out;

  // ---- workspace layout ----
  uint8_t* p = (uint8_t*)d_ws;
  int* counts = (int*)p;            p += 256;
  int* toklist = (int*)p;           p += (size_t)NE * T_TOK * 4;
  float* wts = (float*)p;           p += (size_t)NE * T_TOK * 4;
  unsigned short* xbf = (unsigned short*)p;  p += (size_t)T_TOK * H_DIM * 2;
  unsigned short* WgT = (unsigned short*)p;  p += (size_t)NE * H_DIM * IMOE * 2;
  unsigned short* WuT = (unsigned short*)p;  p += (size_t)NE * H_DIM * IMOE * 2;
  unsigned short* WdT = (unsigned short*)p;  p += (size_t)NE * IMOE * H_DIM * 2;
  unsigned short* WgsT = (unsigned short*)p; p += (size_t)H_DIM * ISHARED * 2;
  unsigned short* WusT = (unsigned short*)p; p += (size_t)H_DIM * ISHARED * 2;
  unsigned short* WdsT = (unsigned short*)p; p += (size_t)ISHARED * H_DIM * 2;
  unsigned short* HhT = (unsigned short*)p;  p += (size_t)NE * T_TOK * IMOE * 2;
  unsigned short* HsT = (unsigned short*)p;  p += (size_t)T_TOK * ISHARED * 2;
  size_t need = (size_t)(p - (uint8_t*)d_ws);
  if (ws_size < need) return;  // fail visibly (harness validates output)

  hipMemsetAsync(d_ws, 0, 64, stream);
  hipMemsetAsync(d_out, 0, (size_t)out_size * 4, stream);

  prepass<<<59520, 256, 0, stream>>>(x, labels, cc, Wg, Wu, Wd, Wgs, Wus, Wds,
                                     xbf, counts, toklist, wts,
                                     WgT, WuT, WdT, WgsT, WusT, WdsT);

  up_merged<<<2288, 512, 0, stream>>>(xbf, WgT, WuT, WgsT, WusT, HhT, HsT,
                                      toklist, counts);

  down_merged<<<1408, 512, 0, stream>>>(HhT, HsT, WdT, WdsT, out,
                                        toklist, wts, counts);
}

// Round 19
// 395.683 us; speedup vs baseline: 1.1813x; 1.0065x over previous
//
#include <hip/hip_runtime.h>
#include <hip/hip_bf16.h>
#include <stdint.h>

#define T_TOK 2048
#define H_DIM 2048
#define S_SEQ 1024
#define NE_ROUTED 8
#define NE 9
#define IMOE 1408
#define ISHARED 5632
#define UNCOND_LBL 1000

typedef short bf16x8 __attribute__((ext_vector_type(8)));
typedef float f32x4 __attribute__((ext_vector_type(4)));

__device__ __forceinline__ unsigned short f2bf(float f) {
  union { float f; unsigned int u; } v; v.f = f;
  unsigned int u = v.u;
  return (unsigned short)((u + 0x7fffu + ((u >> 16) & 1u)) >> 16);
}

__device__ __forceinline__ void gl16(const void* g, void* l) {
  __builtin_amdgcn_global_load_lds(
      (const __attribute__((address_space(1))) unsigned int*)g,
      (__attribute__((address_space(3))) unsigned int*)l, 16, 0, 0);
}

// ============================================================================
// Striped-swizzled bf16 layout: tensor[e][ns][kt][u][8], ns=n/16, kt=k/32,
// logical unit ul = (n&15)*4 + ((k>>3)&3), physical u = ul ^ ((ul>>3)&7).
// ============================================================================

// LDS tile stride 73 (odd) -> ~2-way bank aliasing on both phases (free).
#define TS 73

// Two consecutive kt tiles per block; both global loads issued up-front so
// tile B's HBM latency hides under tile A's LDS store + compute + write.
__device__ __forceinline__ void transpose_pair(
    const float* __restrict__ src, unsigned short* __restrict__ dst,
    int K, int N, int e, int kt0, int n0, int t, float* tile /*[32][TS]*/) {
  int NS = N >> 4, KT = K >> 5;
  const float* sp0 = src + (size_t)e * K * N + (size_t)kt0 * 32 * N + n0;
  int kr = t >> 3, nc = (t & 7) << 3;
  const float* spA = sp0 + (size_t)kr * N + nc;
  const float* spB = spA + (size_t)32 * N;
  float4 a0 = *(const float4*)spA;
  float4 a1 = *(const float4*)(spA + 4);
  float4 b0 = *(const float4*)spB;      // prefetch tile B
  float4 b1 = *(const float4*)(spB + 4);

  int nsl = t >> 6, up = t & 63;
  int ul = up ^ ((up >> 3) & 7);
  int rn = ul >> 2, fq = ul & 3;
  int nl = (nsl << 4) + rn;
  size_t ns = (size_t)e * NS + (n0 >> 4) + nsl;

  // ---- tile A (kt0) ----
  *(float4*)&tile[kr * TS + nc] = a0;
  *(float4*)&tile[kr * TS + nc + 4] = a1;
  __syncthreads();
  {
    unsigned int pk[4];
#pragma unroll
    for (int j = 0; j < 4; j++) {
      float f0 = tile[(fq * 8 + 2 * j) * TS + nl];
      float f1 = tile[(fq * 8 + 2 * j + 1) * TS + nl];
      pk[j] = (unsigned)f2bf(f0) | ((unsigned)f2bf(f1) << 16);
    }
    *(uint4*)(dst + (ns * KT + kt0) * 512 + up * 8) = make_uint4(pk[0], pk[1], pk[2], pk[3]);
  }
  __syncthreads();
  // ---- tile B (kt0+1) ----
  *(float4*)&tile[kr * TS + nc] = b0;
  *(float4*)&tile[kr * TS + nc + 4] = b1;
  __syncthreads();
  {
    unsigned int pk[4];
#pragma unroll
    for (int j = 0; j < 4; j++) {
      float f0 = tile[(fq * 8 + 2 * j) * TS + nl];
      float f1 = tile[(fq * 8 + 2 * j + 1) * TS + nl];
      pk[j] = (unsigned)f2bf(f0) | ((unsigned)f2bf(f1) << 16);
    }
    *(uint4*)(dst + (ns * KT + kt0 + 1) * 512 + up * 8) = make_uint4(pk[0], pk[1], pk[2], pk[3]);
  }
}

// ============================================================================
// PREPASS: cvt + router + all six transposes (2 kt-tiles/block), ONE dispatch.
// blocks: [0,4096) cvt | [4096,4608) router | [4608,32064) transposes
// transpose pairs: Wg 6336 | Wu 6336 | Wd 6336 | Wgs 2816 | Wus 2816 | Wds 2816
// ============================================================================
__global__ __launch_bounds__(256) void prepass(
    const float* __restrict__ x, const int* __restrict__ labels,
    const float* __restrict__ cc,
    const float* __restrict__ Wg, const float* __restrict__ Wu,
    const float* __restrict__ Wd, const float* __restrict__ Wgs,
    const float* __restrict__ Wus, const float* __restrict__ Wds,
    unsigned short* __restrict__ xbf,
    int* __restrict__ counts, int* __restrict__ toklist, float* __restrict__ wts,
    unsigned short* __restrict__ WgT, unsigned short* __restrict__ WuT,
    unsigned short* __restrict__ WdT, unsigned short* __restrict__ WgsT,
    unsigned short* __restrict__ WusT, unsigned short* __restrict__ WdsT) {
  __shared__ float tile[32 * TS];
  int blk = blockIdx.x;
  int tid = threadIdx.x;

  if (blk < 4096) {                       // ---- cvt ----
    int i = (blk * 256 + tid) * 4;
    float4 v = *(const float4*)(x + i);
    uint2 pk;
    pk.x = (unsigned)f2bf(v.x) | ((unsigned)f2bf(v.y) << 16);
    pk.y = (unsigned)f2bf(v.z) | ((unsigned)f2bf(v.w) << 16);
    *(uint2*)(xbf + i) = pk;
    return;
  }
  if (blk < 4608) {                       // ---- router ----
    int t = ((blk - 4096) * 256 + tid) >> 6;
    int lane = tid & 63;
    const float* xp = x + (size_t)t * H_DIM;
    float xx = 0.f;
    float d[NE_ROUTED], cn[NE_ROUTED];
#pragma unroll
    for (int e = 0; e < NE_ROUTED; e++) { d[e] = 0.f; cn[e] = 0.f; }
    for (int h = lane; h < H_DIM; h += 64) {
      float xv = xp[h];
      xx += xv * xv;
#pragma unroll
      for (int e = 0; e < NE_ROUTED; e++) {
        float cv = cc[e * H_DIM + h];
        d[e] += xv * cv;
        cn[e] += cv * cv;
      }
    }
#pragma unroll
    for (int off = 32; off > 0; off >>= 1) {
      xx += __shfl_xor(xx, off);
#pragma unroll
      for (int e = 0; e < NE_ROUTED; e++) {
        d[e] += __shfl_xor(d[e], off);
        cn[e] += __shfl_xor(cn[e], off);
      }
    }
    if (lane == 0) {
      int lab = labels[t / S_SEQ];
      if (lab == UNCOND_LBL) {
        int r = atomicAdd(&counts[NE - 1], 1);
        toklist[(NE - 1) * T_TOK + r] = t;
        wts[(NE - 1) * T_TOK + r] = 1.0f;
      } else {
        float xn = sqrtf(xx + 1e-12f);
        float cosv[NE_ROUTED];
        float mx = -1e30f;
#pragma unroll
        for (int e = 0; e < NE_ROUTED; e++) {
          cosv[e] = d[e] / (xn * sqrtf(cn[e] + 1e-12f));
          mx = fmaxf(mx, cosv[e]);
        }
        float p[NE_ROUTED];
        float s = 0.f;
#pragma unroll
        for (int e = 0; e < NE_ROUTED; e++) { p[e] = __expf(cosv[e] - mx); s += p[e]; }
        int i1 = 0;
#pragma unroll
        for (int e = 1; e < NE_ROUTED; e++) if (p[e] > p[i1]) i1 = e;
        int i2 = (i1 == 0) ? 1 : 0;
#pragma unroll
        for (int e = 0; e < NE_ROUTED; e++) if (e != i2 && e != i1 && p[e] > p[i2]) i2 = e;
        int r1 = atomicAdd(&counts[i1], 1);
        toklist[i1 * T_TOK + r1] = t;
        wts[i1 * T_TOK + r1] = p[i1] / s;
        int r2 = atomicAdd(&counts[i2], 1);
        toklist[i2 * T_TOK + r2] = t;
        wts[i2 * T_TOK + r2] = p[i2] / s;
      }
    }
    return;
  }
  int lid = blk - 4608;
  if (lid < 6336) {                        // Wg: pairs 32 x 22 per expert
    int e = lid / 704, r = lid % 704;
    int kt0 = (r / 22) * 2, n0 = (r % 22) << 6;
    transpose_pair(Wg, WgT, H_DIM, IMOE, e, kt0, n0, tid, tile);
  } else if (lid < 12672) {                // Wu
    int r0 = lid - 6336;
    int e = r0 / 704, r = r0 % 704;
    int kt0 = (r / 22) * 2, n0 = (r % 22) << 6;
    transpose_pair(Wu, WuT, H_DIM, IMOE, e, kt0, n0, tid, tile);
  } else if (lid < 19008) {                // Wd: pairs 22 x 32 per expert
    int r0 = lid - 12672;
    int e = r0 / 704, r = r0 % 704;
    int kt0 = (r / 32) * 2, n0 = (r % 32) << 6;
    transpose_pair(Wd, WdT, IMOE, H_DIM, e, kt0, n0, tid, tile);
  } else if (lid < 21824) {                // Wgs: pairs 32 x 88
    int r = lid - 19008;
    int kt0 = (r / 88) * 2, n0 = (r % 88) << 6;
    transpose_pair(Wgs, WgsT, H_DIM, ISHARED, 0, kt0, n0, tid, tile);
  } else if (lid < 24640) {                // Wus
    int r = lid - 21824;
    int kt0 = (r / 88) * 2, n0 = (r % 88) << 6;
    transpose_pair(Wus, WusT, H_DIM, ISHARED, 0, kt0, n0, tid, tile);
  } else {                                 // Wds: pairs 88 x 32
    int r = lid - 24640;
    int kt0 = (r / 32) * 2, n0 = (r % 32) << 6;
    transpose_pair(Wds, WdsT, ISHARED, H_DIM, 0, kt0, n0, tid, tile);
  }
}

// ---- inline descriptor lookup ----
__device__ __forceinline__ bool up_desc(const int* counts, int d,
                                        bool* sh, int* e, int* nt, int* mt) {
  int mtm[NE];
  int nv = 704;
#pragma unroll
  for (int k = 0; k < NE; k++) {
    int c = counts[k];
    int m = (c + 127) >> 7; if (m > 16) m = 16;
    mtm[k] = m;
    nv += m * 11;
  }
  int q = nv >> 3, r = nv & 7;
  int x = d & 7, j = d >> 3;
  int cap = q + (x < r ? 1 : 0);
  if (j >= cap) return false;
  int idx = (x < r ? x * (q + 1) : r * (q + 1) + (x - r) * q) + j;
  if (idx < 704) {
    *sh = true; *e = 0; *nt = idx >> 4; *mt = idx & 15;
    return true;
  }
  idx -= 704;
#pragma unroll
  for (int k = 0; k < NE; k++) {
    int n = mtm[k] * 11;
    if (idx < n) {
      *sh = false; *e = k; *nt = idx / mtm[k]; *mt = idx % mtm[k];
      return true;
    }
    idx -= n;
  }
  return false;
}

__device__ __forceinline__ bool down_desc(const int* counts, int d,
                                          bool* sh, int* e, int* nt, int* mt, int* kc) {
  int x = d & 7, j = d >> 3;
  if (j < 32) {
    *sh = true; *e = 0; *nt = x; *mt = j >> 1; *kc = j & 1;
    return true;
  }
  int mtm[NE];
  int R = 0;
#pragma unroll
  for (int k = 0; k < NE; k++) {
    int c = counts[k];
    int m = (c + 127) >> 7; if (m > 16) m = 16;
    mtm[k] = m;
    R += m * 8;
  }
  int jr = j - 32;
  int q = R >> 3, r = R & 7;
  int cap = q + (x < r ? 1 : 0);
  if (jr >= cap) return false;
  int idx = (x < r ? x * (q + 1) : r * (q + 1) + (x - r) * q) + jr;
#pragma unroll
  for (int k = 0; k < NE; k++) {
    int n = mtm[k] * 8;
    if (idx < n) {
      *sh = false; *e = k; *nt = idx / mtm[k]; *mt = idx % mtm[k]; *kc = 0;
      return true;
    }
    idx -= n;
  }
  return false;
}

// ============================================================================
// Merged fused gate+up GEMM (round-17 verbatim): 8 waves, BM=128 BN=128,
// ring-3 (72 KB -> 2 blk/CU), 3 gl16/wave/step, vmcnt(3)/(0) depth-2.
// ============================================================================
__global__ __launch_bounds__(512, 4) void up_merged(
    const unsigned short* __restrict__ X,
    const unsigned short* __restrict__ WgT, const unsigned short* __restrict__ WuT,
    const unsigned short* __restrict__ WgsT, const unsigned short* __restrict__ WusT,
    unsigned short* __restrict__ HhT, unsigned short* __restrict__ HsT,
    const int* __restrict__ toklist, const int* __restrict__ counts) {
  const int KT = 64;
  bool sh; int e, nt, mt;
  if (!up_desc(counts, blockIdx.x, &sh, &e, &nt, &mt)) return;

  int cnt = sh ? T_TOK : counts[e];
  int m0 = mt * 128;
  if (m0 >= cnt) return;
  int n0 = nt * 128;
  int NS = sh ? (ISHARED >> 4) : (IMOE >> 4);
  int KTO = sh ? (ISHARED >> 5) : (IMOE >> 5);
  unsigned short* Hout = sh ? HsT : HhT;
  size_t hb = sh ? 0 : (size_t)e * (T_TOK >> 4);

  __shared__ unsigned short As[3][4096];
  __shared__ unsigned short Bgs[3][4096];
  __shared__ unsigned short Bus[3][4096];

  int tid = threadIdx.x, lane = tid & 63, wid = tid >> 6;
  int wm = wid >> 2, wn = wid & 3;
  int fr = lane & 15, fq = lane >> 4;

  int v = lane ^ ((lane >> 3) & 7);
  int rr = m0 + wid * 16 + (v >> 2);
  if (rr >= cnt) rr = cnt - 1;
  int tok = sh ? rr : toklist[e * T_TOK + rr];
  const unsigned short* aptr = X + (size_t)tok * H_DIM + ((v & 3) << 3);

  size_t nsg = (sh ? 0 : (size_t)e * NS) + (n0 >> 4) + wid;
  const unsigned short* bgp = (sh ? WgsT : WgT) + nsg * KT * 512 + lane * 8;
  const unsigned short* bup = (sh ? WusT : WuT) + nsg * KT * 512 + lane * 8;

  int fo = fr * 4 + fq;
  fo = (fo ^ ((fo >> 3) & 7)) * 8;

  f32x4 zero = {0.f, 0.f, 0.f, 0.f};
  f32x4 accg[4][2], accu[4][2];
#pragma unroll
  for (int i = 0; i < 4; i++)
#pragma unroll
    for (int jj = 0; jj < 2; jj++) { accg[i][jj] = zero; accu[i][jj] = zero; }

  auto stage = [&](int b, int t) {
    gl16(aptr + (size_t)t * 32, &As[b][wid * 512]);
    gl16(bgp + (size_t)t * 512, &Bgs[b][wid * 512]);
    gl16(bup + (size_t)t * 512, &Bus[b][wid * 512]);
  };

  stage(0, 0);
  stage(1, 1);
  asm volatile("s_waitcnt vmcnt(3)" ::: "memory");
  __builtin_amdgcn_s_barrier();

  for (int t = 0; t < KT; ++t) {
    int b = t % 3;
    bf16x8 af[4], bgf[2], buf2[2];
#pragma unroll
    for (int mi = 0; mi < 4; mi++)
      af[mi] = *(const bf16x8*)&As[b][(wm * 4 + mi) * 512 + fo];
#pragma unroll
    for (int ni = 0; ni < 2; ni++) {
      bgf[ni] = *(const bf16x8*)&Bgs[b][(wn * 2 + ni) * 512 + fo];
      buf2[ni] = *(const bf16x8*)&Bus[b][(wn * 2 + ni) * 512 + fo];
    }
    if (t + 2 < KT) {
      int nb = t + 2; nb %= 3;
      stage(nb, t + 2);
    }
    __builtin_amdgcn_s_setprio(1);
#pragma unroll
    for (int mi = 0; mi < 4; mi++)
#pragma unroll
      for (int ni = 0; ni < 2; ni++) {
        accg[mi][ni] = __builtin_amdgcn_mfma_f32_16x16x32_bf16(af[mi], bgf[ni], accg[mi][ni], 0, 0, 0);
        accu[mi][ni] = __builtin_amdgcn_mfma_f32_16x16x32_bf16(af[mi], buf2[ni], accu[mi][ni], 0, 0, 0);
      }
    __builtin_amdgcn_s_setprio(0);
    if (t + 2 < KT) {
      asm volatile("s_waitcnt vmcnt(3)" ::: "memory");
      __builtin_amdgcn_s_barrier();
    } else if (t + 1 < KT) {
      asm volatile("s_waitcnt vmcnt(0)" ::: "memory");
      __builtin_amdgcn_s_barrier();
    }
  }

#pragma unroll
  for (int mi = 0; mi < 4; mi++) {
    int rb = m0 + wm * 64 + mi * 16;
    if (rb >= cnt) continue;
    int ms = rb >> 4;
#pragma unroll
    for (int ni = 0; ni < 2; ni++) {
      int col = n0 + wn * 32 + ni * 16 + fr;
      int kto = col >> 5;
      int c3 = (col >> 3) & 3;
      int jcol = col & 7;
      size_t base = ((hb + ms) * (size_t)KTO + kto) * 512 + jcol;
#pragma unroll
      for (int jj = 0; jj < 4; jj++) {
        int row = rb + fq * 4 + jj;
        if (row < cnt) {
          float g = accg[mi][ni][jj];
          float u = accu[mi][ni][jj];
          float h = g / (1.f + __expf(-g)) * u;
          int ul = (fq * 4 + jj) * 4 + c3;
          int ph = ul ^ ((ul >> 3) & 7);
          Hout[base + ph * 8] = f2bf(h);
        }
      }
    }
  }
}

// ============================================================================
// Merged down GEMM (round-17 verbatim): 8 waves, BM=128 BN=256, ring-3 72 KB
// -> 2 blk/CU, vmcnt(3)/(0) depth-2, shared K-split x2, inline descriptor map.
// ============================================================================
__global__ __launch_bounds__(512, 4) void down_merged(
    const unsigned short* __restrict__ HhT, const unsigned short* __restrict__ HsT,
    const unsigned short* __restrict__ WdT, const unsigned short* __restrict__ WdsT,
    float* __restrict__ Out,
    const int* __restrict__ toklist, const float* __restrict__ wts,
    const int* __restrict__ counts) {
  bool sh; int e, nt, mt, kc;
  if (!down_desc(counts, blockIdx.x, &sh, &e, &nt, &mt, &kc)) return;

  int cnt = sh ? T_TOK : counts[e];
  int m0 = mt * 128;
  if (m0 >= cnt) return;
  int n0 = nt * 256;
  int KTfull = sh ? (ISHARED >> 5) : (IMOE >> 5);
  int KT = sh ? 88 : 44;
  int koff = kc * 88;
  const int NS = H_DIM >> 4;

  __shared__ unsigned short As[3][4096];
  __shared__ unsigned short Bs[3][8192];

  int tid = threadIdx.x, lane = tid & 63, wid = tid >> 6;
  int wm = wid >> 2, wn = wid & 3;
  int fr = lane & 15, fq = lane >> 4;

  const unsigned short* Hin = sh ? HsT : HhT;
  size_t mbase = sh ? 0 : (size_t)e * (T_TOK >> 4);
  size_t ms = mbase + (m0 >> 4) + wid;
  const unsigned short* ap = Hin + ms * (size_t)KTfull * 512 + lane * 8;
  const unsigned short* WdBase = sh ? WdsT : WdT;
  size_t nsbase = (sh ? 0 : (size_t)e * NS) + (n0 >> 4);
  const unsigned short* bp0 = WdBase + (nsbase + wid * 2) * (size_t)KTfull * 512 + lane * 8;
  const unsigned short* bp1 = WdBase + (nsbase + wid * 2 + 1) * (size_t)KTfull * 512 + lane * 8;

  int fo = fr * 4 + fq;
  fo = (fo ^ ((fo >> 3) & 7)) * 8;

  f32x4 zero = {0.f, 0.f, 0.f, 0.f};
  f32x4 acc[4][4];
#pragma unroll
  for (int i = 0; i < 4; i++)
#pragma unroll
    for (int jj = 0; jj < 4; jj++) acc[i][jj] = zero;

  auto stage = [&](int b, int t) {
    gl16(ap + (size_t)(koff + t) * 512, &As[b][wid * 512]);
    gl16(bp0 + (size_t)(koff + t) * 512, &Bs[b][(wid * 2) * 512]);
    gl16(bp1 + (size_t)(koff + t) * 512, &Bs[b][(wid * 2 + 1) * 512]);
  };

  stage(0, 0);
  stage(1, 1);
  asm volatile("s_waitcnt vmcnt(3)" ::: "memory");
  __builtin_amdgcn_s_barrier();

  for (int t = 0; t < KT; ++t) {
    int b = t % 3;
    bf16x8 af[4], bf[4];
#pragma unroll
    for (int mi = 0; mi < 4; mi++)
      af[mi] = *(const bf16x8*)&As[b][(wm * 4 + mi) * 512 + fo];
#pragma unroll
    for (int ni = 0; ni < 4; ni++)
      bf[ni] = *(const bf16x8*)&Bs[b][(wn * 4 + ni) * 512 + fo];
    if (t + 2 < KT) {
      int nb = t + 2; nb %= 3;
      stage(nb, t + 2);
    }
    __builtin_amdgcn_s_setprio(1);
#pragma unroll
    for (int mi = 0; mi < 4; mi++)
#pragma unroll
      for (int ni = 0; ni < 4; ni++)
        acc[mi][ni] = __builtin_amdgcn_mfma_f32_16x16x32_bf16(af[mi], bf[ni], acc[mi][ni], 0, 0, 0);
    __builtin_amdgcn_s_setprio(0);
    if (t + 2 < KT) {
      asm volatile("s_waitcnt vmcnt(3)" ::: "memory");
      __builtin_amdgcn_s_barrier();
    } else if (t + 1 < KT) {
      asm volatile("s_waitcnt vmcnt(0)" ::: "memory");
      __builtin_amdgcn_s_barrier();
    }
  }

  int rbase = m0 + wm * 64;
  int cbase = n0 + wn * 64;
#pragma unroll
  for (int mi = 0; mi < 4; mi++)
#pragma unroll
    for (int ni = 0; ni < 4; ni++) {
      int col = cbase + ni * 16 + fr;
#pragma unroll
      for (int jj = 0; jj < 4; jj++) {
        int row = rbase + mi * 16 + fq * 4 + jj;
        if (row < cnt) {
          float vv = acc[mi][ni][jj];
          int tk;
          float wgt;
          if (sh) { tk = row; wgt = 1.0f; }
          else { tk = toklist[e * T_TOK + row]; wgt = wts[e * T_TOK + row]; }
          atomicAdd(&Out[(size_t)tk * H_DIM + col], wgt * vv);
        }
      }
    }
}

extern "C" void kernel_launch(void* const* d_in, const int* in_sizes, int n_in,
                              void* d_out, int out_size, void* d_ws, size_t ws_size,
                              hipStream_t stream) {
  const float* x = (const float*)d_in[0];
  const int* labels = (const int*)d_in[1];
  const float* cc = (const float*)d_in[2];
  const float* Wg = (const float*)d_in[3];
  const float* Wu = (const float*)d_in[4];
  const float* Wd = (const float*)d_in[5];
  const float* Wgs = (const float*)d_in[6];
  const float* Wus = (const float*)d_in[7];
  const float* Wds = (const float*)d_in[8];
  float* out = (float*)d_out;

  // ---- workspace layout ----
  uint8_t* p = (uint8_t*)d_ws;
  int* counts = (int*)p;            p += 256;
  int* toklist = (int*)p;           p += (size_t)NE * T_TOK * 4;
  float* wts = (float*)p;           p += (size_t)NE * T_TOK * 4;
  unsigned short* xbf = (unsigned short*)p;  p += (size_t)T_TOK * H_DIM * 2;
  unsigned short* WgT = (unsigned short*)p;  p += (size_t)NE * H_DIM * IMOE * 2;
  unsigned short* WuT = (unsigned short*)p;  p += (size_t)NE * H_DIM * IMOE * 2;
  unsigned short* WdT = (unsigned short*)p;  p += (size_t)NE * IMOE * H_DIM * 2;
  unsigned short* WgsT = (unsigned short*)p; p += (size_t)H_DIM * ISHARED * 2;
  unsigned short* WusT = (unsigned short*)p; p += (size_t)H_DIM * ISHARED * 2;
  unsigned short* WdsT = (unsigned short*)p; p += (size_t)ISHARED * H_DIM * 2;
  unsigned short* HhT = (unsigned short*)p;  p += (size_t)NE * T_TOK * IMOE * 2;
  unsigned short* HsT = (unsigned short*)p;  p += (size_t)T_TOK * ISHARED * 2;
  size_t need = (size_t)(p - (uint8_t*)d_ws);
  if (ws_size < need) return;  // fail visibly (harness validates output)

  hipMemsetAsync(d_ws, 0, 64, stream);
  hipMemsetAsync(d_out, 0, (size_t)out_size * 4, stream);

  prepass<<<32064, 256, 0, stream>>>(x, labels, cc, Wg, Wu, Wd, Wgs, Wus, Wds,
                                     xbf, counts, toklist, wts,
                                     WgT, WuT, WdT, WgsT, WusT, WdsT);

  up_merged<<<2288, 512, 0, stream>>>(xbf, WgT, WuT, WgsT, WusT, HhT, HsT,
                                      toklist, counts);

  down_merged<<<1408, 512, 0, stream>>>(HhT, HsT, WdT, WdsT, out,
                                        toklist, wts, counts);
}